// Round 7
// baseline (455.965 us; speedup 1.0000x reference)
//
#include <hip/hip_runtime.h>
#include <hip/hip_bf16.h>

#define B_N 4
#define S_LEN 2048
#define D_MODEL 1024
#define N_HEAD 16
#define D_HEAD 64
#define M_ROWS (B_N * S_LEN) /* 8192 */

typedef short bf16x8 __attribute__((ext_vector_type(8)));
typedef short bf16x4 __attribute__((ext_vector_type(4)));
typedef float f32x4 __attribute__((ext_vector_type(4)));

#if __has_builtin(__builtin_amdgcn_mfma_f32_16x16x16bf16_1k)
#define HAVE_MFMA16 1
#else
#define HAVE_MFMA16 0
#endif

__device__ __forceinline__ unsigned short f2bf(float f) {
  union { float f; unsigned int u; } v; v.f = f;
  unsigned int r = v.u + 0x7FFFu + ((v.u >> 16) & 1u);
  return (unsigned short)(r >> 16);
}
__device__ __forceinline__ float bf2f(unsigned short u) {
  union { unsigned int u; float f; } v; v.u = ((unsigned int)u) << 16;
  return v.f;
}
// packed f32x2 -> bf16x2 (v_cvt_pk_bf16_f32, RNE)
__device__ __forceinline__ unsigned int pkbf(float a, float b) {
  union { __hip_bfloat162 h; unsigned int u; } cv;
  cv.h = __float22bfloat162_rn(make_float2(a, b));
  return cv.u;
}
__device__ __forceinline__ bf16x8 ld8(const unsigned short* p) {
  return *reinterpret_cast<const bf16x8*>(p);
}
__device__ __forceinline__ bf16x4 ld4(const unsigned short* p) {
  return *reinterpret_cast<const bf16x4*>(p);
}
__device__ __forceinline__ void glds16(const unsigned short* g, unsigned short* l) {
  __builtin_amdgcn_global_load_lds(
      (const __attribute__((address_space(1))) unsigned int*)g,
      (__attribute__((address_space(3))) unsigned int*)l, 16, 0, 0);
}

// ---------------------------------------------------------------- rope table
__global__ __launch_bounds__(256) void rope_tab_k(const int* __restrict__ pos,
                                                  float2* __restrict__ tab) {
  const int idx = blockIdx.x * 256 + threadIdx.x;
  const int s = idx >> 5;
  const int i = idx & 31;
  const float inv = exp2f(-(float)i * 0.41524101186092029f);  // log2(1e4)/32
  const float ang = (float)pos[s] * inv;
  tab[idx] = make_float2(cosf(ang), sinf(ang));
}

// ---------------------------------------------------------------- cast x
__global__ __launch_bounds__(256) void cast_k(const float* __restrict__ X,
                                              unsigned short* __restrict__ Y) {
  const size_t i = ((size_t)blockIdx.x * 256 + threadIdx.x) * 8;
  const float4 a = *reinterpret_cast<const float4*>(X + i);
  const float4 b = *reinterpret_cast<const float4*>(X + i + 4);
  union { unsigned int u[4]; uint4 v; } o;
  o.u[0] = pkbf(a.x, a.y); o.u[1] = pkbf(a.z, a.w);
  o.u[2] = pkbf(b.x, b.y); o.u[3] = pkbf(b.z, b.w);
  *reinterpret_cast<uint4*>(Y + i) = o.v;
}

// ---------------------------------------------------------------- transpose
__global__ __launch_bounds__(256) void wtrans_k(
    const float* __restrict__ W0, const float* __restrict__ W1,
    const float* __restrict__ W2, const float* __restrict__ W3,
    unsigned short* __restrict__ T0, unsigned short* __restrict__ T1,
    unsigned short* __restrict__ T2, unsigned short* __restrict__ T3) {
  const int z = blockIdx.z;
  const float* __restrict__ W = (z == 0) ? W0 : (z == 1) ? W1 : (z == 2) ? W2 : W3;
  unsigned short* __restrict__ T = (z == 0) ? T0 : (z == 1) ? T1 : (z == 2) ? T2 : T3;
  __shared__ __align__(16) unsigned short tile[64][72];
  const int kb = blockIdx.x * 64;
  const int nb = blockIdx.y * 64;
#pragma unroll
  for (int it = 0; it < 2; ++it) {
    const int chunk = it * 256 + threadIdx.x;
    const int r = chunk >> 3;
    const int c8 = (chunk & 7) * 8;
    const float* src = W + (size_t)(kb + r) * D_MODEL + nb + c8;
    const float4 a = *reinterpret_cast<const float4*>(src);
    const float4 b = *reinterpret_cast<const float4*>(src + 4);
    union { unsigned int u[4]; uint4 v; } o;
    o.u[0] = pkbf(a.x, a.y); o.u[1] = pkbf(a.z, a.w);
    o.u[2] = pkbf(b.x, b.y); o.u[3] = pkbf(b.z, b.w);
    *reinterpret_cast<uint4*>(&tile[r][c8]) = o.v;
  }
  __syncthreads();
#pragma unroll
  for (int it = 0; it < 2; ++it) {
    const int chunk = it * 256 + threadIdx.x;
    const int n = chunk >> 3;
    const int k8 = (chunk & 7) * 8;
    __align__(16) unsigned short vals[8];
#pragma unroll
    for (int j = 0; j < 8; ++j) vals[j] = tile[k8 + j][n];
    *reinterpret_cast<uint4*>(T + (size_t)(nb + n) * D_MODEL + kb + k8) =
        *reinterpret_cast<const uint4*>(vals);
  }
}

// ---------------------------------------------------------------- GEMM (proj)
// 128x128 tile, BK=32, global_load_lds staging, 4 waves x (4x4 frags).
__global__ __launch_bounds__(256) void gemm2_k(
    const unsigned short* __restrict__ A, const unsigned short* __restrict__ W,
    float* __restrict__ OF) {
  __shared__ __align__(16) unsigned short smem[4][64][68];
  unsigned short* As = &smem[0][0][0];
  unsigned short* Bs = As + 128 * 32;

  const int tid = threadIdx.x;
  const int lane = tid & 63;
  const int w = tid >> 6;
  const int l15 = lane & 15;
  const int l4 = lane >> 4;

  const int row0 = blockIdx.x * 128;
  const int col0 = blockIdx.y * 128;

  const int srow = w * 32 + (lane >> 2);
  const int scol = (lane & 3) * 8;
  const unsigned short* ga = A + (size_t)(row0 + srow) * D_MODEL + scol;
  const unsigned short* gb = W + (size_t)(col0 + srow) * D_MODEL + scol;
  unsigned short* la = &As[(w * 32) * 32];
  unsigned short* lb = &Bs[(w * 32) * 32];

  const int wrow = (w & 1) * 64;
  const int wcol = (w >> 1) * 64;

  f32x4 acc[4][4];
  const f32x4 fz = {0.f, 0.f, 0.f, 0.f};
#pragma unroll
  for (int m = 0; m < 4; ++m)
#pragma unroll
    for (int n = 0; n < 4; ++n) acc[m][n] = fz;

  for (int kb = 0; kb < D_MODEL; kb += 32) {
    glds16(ga + kb, la);
    glds16(ga + 16 * D_MODEL + kb, la + 16 * 32);
    glds16(gb + kb, lb);
    glds16(gb + 16 * D_MODEL + kb, lb + 16 * 32);
    __syncthreads();
    bf16x8 af[4], bfr[4];
#pragma unroll
    for (int m = 0; m < 4; ++m) af[m] = ld8(&As[(wrow + m * 16 + l15) * 32 + l4 * 8]);
#pragma unroll
    for (int n = 0; n < 4; ++n) bfr[n] = ld8(&Bs[(wcol + n * 16 + l15) * 32 + l4 * 8]);
#pragma unroll
    for (int m = 0; m < 4; ++m)
#pragma unroll
      for (int n = 0; n < 4; ++n)
        acc[m][n] = __builtin_amdgcn_mfma_f32_16x16x32_bf16(af[m], bfr[n], acc[m][n], 0, 0, 0);
    __syncthreads();
  }

#pragma unroll
  for (int n = 0; n < 4; ++n) {
    const int gcol = col0 + wcol + n * 16 + l15;
#pragma unroll
    for (int m = 0; m < 4; ++m)
#pragma unroll
      for (int r = 0; r < 4; ++r)
        OF[(size_t)(row0 + wrow + m * 16 + l4 * 4 + r) * D_MODEL + gcol] = acc[m][n][r];
  }
}

// ---------------------------------------------------------------- QKV GEMM
// m201-template port: 256x256 tile, BK=64, 8 waves (2M x 4N, wave-tile
// 128x64), LDS 128 KiB [slot2][A/B][half2][128x64].  Per iteration (K-tiles
// u=2i slot0, v=2i+1 slot1): 8 phases, each = {12 swizzled ds_read_b128 (one
// C-quadrant) | stage 1 half-tile (2 glds) | barrier | setprio(1) 16 MFMA
// setprio(0) | [vmcnt(2) at P3/P7] | barrier}.
// Stage schedule (region freed >=2 barrier-pairs before stage; ledger
// verified): P0:B0(v) P1:A1(v) P2:B1(v) P3:A0(u+2) P4:B0(u+2) P5:A1(u+2)
// P6:B1(u+2) P7:A0(v+2).  vmcnt(2)+barrier at P3-end guards all of v for
// P4-P7; at P7-end guards all of u+2 for next P0-P3.  vmcnt(0) only at i=7.
// Swizzle: physical 16B chunk = logical ^ (row&7) on stage source AND ds_read.
__global__ __launch_bounds__(512, 1) void gemm9_k(
    const unsigned short* __restrict__ A, const unsigned short* __restrict__ W,
    unsigned short* __restrict__ Qo, unsigned short* __restrict__ Ko,
    unsigned short* __restrict__ VTo, const float2* __restrict__ tab) {
  __shared__ __align__(16) unsigned short smem[2][2][2][128 * 64];  // 128 KiB

  const int tid = threadIdx.x;
  const int lane = tid & 63;
  const int w = tid >> 6;   // 0..7
  const int l15 = lane & 15;
  const int l4 = lane >> 4;
  const int wm = w >> 2;    // 0..1 : 128-row M-half
  const int wn = w & 3;     // 0..3 : 64-col N-quarter
  const int hb = wn >> 1;   // B half this wave reads
  const int rbb = (wn & 1) * 64;  // B row base within half

  const int row0 = blockIdx.x * 256;
  const int col0 = blockIdx.y * 256;

  // Staging: wave w, call j covers rows w*16+j*8+(lane>>3) of a 128-row half;
  // global chunk pre-swizzled (lane&7)^(row&7); LDS dest linear.
  const int srow8 = lane >> 3;            // 0..7 == row&7 of staged row
  const int schunk = (lane & 7) ^ srow8;  // swizzled 16B chunk
  const unsigned short* gA = A + (size_t)(row0 + w * 16 + srow8) * D_MODEL + schunk * 8;
  const unsigned short* gB = W + (size_t)(col0 + w * 16 + srow8) * D_MODEL + schunk * 8;

  // ds_read chunk offsets (shorts) for the two K-halves; row&7 == l15&7.
  const int swz = l15 & 7;
  const int kc0 = (l4 ^ swz) * 8;
  const int kc1 = ((l4 + 4) ^ swz) * 8;

  f32x4 acc[8][4];
  const f32x4 fz = {0.f, 0.f, 0.f, 0.f};
#pragma unroll
  for (int m = 0; m < 8; ++m)
#pragma unroll
    for (int n = 0; n < 4; ++n) acc[m][n] = fz;

  // stage one half-tile: AB 0=A 1=B, half HA, K-tile T, into slot SL
#define STG(SL, AB, HA, T)                                                     \
  do {                                                                         \
    const unsigned short* g_ =                                                 \
        ((AB) ? gB : gA) + (size_t)(HA) * 128 * D_MODEL + (size_t)(T) * 64;    \
    unsigned short* d_ = &smem[SL][AB][HA][w * 1024];                          \
    glds16(g_, d_);                                                            \
    glds16(g_ + 8 * D_MODEL, d_ + 512);                                        \
  } while (0)

  // one phase: quadrant (QM,QN) of slot SL; STGX issued pre-barrier; TAILW
  // (vmcnt) sits between setprio(0) and the trailing barrier.
#define PH(SL, QM, QN, STGX, TAILW)                                            \
  do {                                                                         \
    bf16x8 af_[4][2], bf_[2][2];                                               \
    _Pragma("unroll") for (int mi = 0; mi < 4; ++mi) {                         \
      const int ra_ = ((QM) * 64 + mi * 16 + l15) * 64;                        \
      af_[mi][0] = ld8(&smem[SL][0][wm][ra_ + kc0]);                           \
      af_[mi][1] = ld8(&smem[SL][0][wm][ra_ + kc1]);                           \
    }                                                                          \
    _Pragma("unroll") for (int ni = 0; ni < 2; ++ni) {                         \
      const int rb_ = (rbb + (QN) * 32 + ni * 16 + l15) * 64;                  \
      bf_[ni][0] = ld8(&smem[SL][1][hb][rb_ + kc0]);                           \
      bf_[ni][1] = ld8(&smem[SL][1][hb][rb_ + kc1]);                           \
    }                                                                          \
    STGX;                                                                      \
    __builtin_amdgcn_s_barrier();                                              \
    __builtin_amdgcn_s_setprio(1);                                             \
    _Pragma("unroll") for (int mi = 0; mi < 4; ++mi)                           \
      _Pragma("unroll") for (int ni = 0; ni < 2; ++ni) {                       \
        acc[(QM) * 4 + mi][(QN) * 2 + ni] =                                    \
            __builtin_amdgcn_mfma_f32_16x16x32_bf16(                           \
                af_[mi][0], bf_[ni][0], acc[(QM) * 4 + mi][(QN) * 2 + ni],     \
                0, 0, 0);                                                      \
        acc[(QM) * 4 + mi][(QN) * 2 + ni] =                                    \
            __builtin_amdgcn_mfma_f32_16x16x32_bf16(                           \
                af_[mi][1], bf_[ni][1], acc[(QM) * 4 + mi][(QN) * 2 + ni],     \
                0, 0, 0);                                                      \
      }                                                                        \
    __builtin_amdgcn_s_setprio(0);                                             \
    TAILW;                                                                     \
    __builtin_amdgcn_s_barrier();                                              \
  } while (0)

#define VM2 asm volatile("s_waitcnt vmcnt(2)" ::: "memory")
#define VM0 asm volatile("s_waitcnt vmcnt(0)" ::: "memory")
#define NOP ((void)0)

  // Prologue: tile0 (all 4 halves) + A0 of tile1 = 10 loads/thread
  STG(0, 0, 0, 0); STG(0, 1, 0, 0); STG(0, 0, 1, 0); STG(0, 1, 1, 0);
  STG(1, 0, 0, 1);
  VM2;  // tile0 fully landed (A0(1) may fly)
  __builtin_amdgcn_s_barrier();

  for (int i = 0; i < 8; ++i) {
    const int v = 2 * i + 1;
    const int u2 = 2 * i + 2;
    if (i < 7) {
      PH(0, 0, 0, STG(1, 1, 0, v), NOP);   // P0: stage B0(v)
      PH(0, 0, 1, STG(1, 0, 1, v), NOP);   // P1: stage A1(v)
      PH(0, 1, 0, STG(1, 1, 1, v), NOP);   // P2: stage B1(v)
      PH(0, 1, 1, STG(0, 0, 0, u2), VM2);  // P3: stage A0(u+2); guard v
      PH(1, 0, 0, STG(0, 1, 0, u2), NOP);  // P4: stage B0(u+2)
      PH(1, 0, 1, STG(0, 0, 1, u2), NOP);  // P5: stage A1(u+2)
      PH(1, 1, 0, STG(0, 1, 1, u2), NOP);  // P6: stage B1(u+2)
      PH(1, 1, 1, STG(1, 0, 0, u2 + 1), VM2);  // P7: stage A0(v+2); guard u+2
    } else {
      PH(0, 0, 0, STG(1, 1, 0, v), NOP);
      PH(0, 0, 1, STG(1, 0, 1, v), NOP);
      PH(0, 1, 0, STG(1, 1, 1, v), NOP);
      PH(0, 1, 1, NOP, VM0);               // final drain
      PH(1, 0, 0, NOP, NOP);
      PH(1, 0, 1, NOP, NOP);
      PH(1, 1, 0, NOP, NOP);
      PH(1, 1, 1, NOP, NOP);
    }
  }
#undef STG
#undef PH
#undef VM2
#undef VM0
#undef NOP

  // ---------------- epilogue: rope (Q/K) or transpose (V); wave does its
  // 128x64 output in 2 passes of 64 rows through wave-private LDS.
  unsigned short(*T)[68] =
      (unsigned short(*)[68])((unsigned short*)smem + w * 4352);  // 64x68
  const int gcb = col0 + wn * 64;  // 64-aligned -> one head per wave
  const bool isV = (gcb >= 2048);
  const int lr = lane >> 3;
  const int lc = lane & 7;

#pragma unroll
  for (int p = 0; p < 2; ++p) {
    if (!isV) {
#pragma unroll
      for (int mi = 0; mi < 4; ++mi)
#pragma unroll
        for (int n = 0; n < 4; ++n)
#pragma unroll
          for (int r = 0; r < 4; ++r)
            T[mi * 16 + l4 * 4 + r][n * 16 + l15] = f2bf(acc[p * 4 + mi][n][r]);
    } else {
#pragma unroll
      for (int mi = 0; mi < 4; ++mi)
#pragma unroll
        for (int n = 0; n < 4; ++n)
#pragma unroll
          for (int r = 0; r < 4; ++r)
            T[n * 16 + l15][mi * 16 + l4 * 4 + r] = f2bf(acc[p * 4 + mi][n][r]);
    }
    if (!isV) {
      const bool isQ = (gcb < 1024);
      unsigned short* O = isQ ? Qo : Ko;
      // fold softmax scale into Q: 1/sqrt(64) * log2(e)
      const float qs = isQ ? 0.18033688011112042f : 1.0f;
      const int cbase = gcb & 1023;
#pragma unroll
      for (int rg = 0; rg < 8; ++rg) {
        const int trow = rg * 8 + lr;
        const int grow = row0 + wm * 128 + p * 64 + trow;
        const int s = grow & (S_LEN - 1);
        const bf16x8 vv = ld8(&T[trow][lc * 8]);
        const float4 tA = *reinterpret_cast<const float4*>(&tab[s * 32 + lc * 4]);
        const float4 tB = *reinterpret_cast<const float4*>(&tab[s * 32 + lc * 4 + 2]);
        float x[8];
#pragma unroll
        for (int j = 0; j < 8; ++j) x[j] = bf2f((unsigned short)vv[j]);
        union { unsigned int u[4]; uint4 v; } o;
        o.u[0] = pkbf((x[0] * tA.x - x[1] * tA.y) * qs, (x[0] * tA.y + x[1] * tA.x) * qs);
        o.u[1] = pkbf((x[2] * tA.z - x[3] * tA.w) * qs, (x[2] * tA.w + x[3] * tA.z) * qs);
        o.u[2] = pkbf((x[4] * tB.x - x[5] * tB.y) * qs, (x[4] * tB.y + x[5] * tB.x) * qs);
        o.u[3] = pkbf((x[6] * tB.z - x[7] * tB.w) * qs, (x[6] * tB.w + x[7] * tB.z) * qs);
        *reinterpret_cast<uint4*>(O + (size_t)grow * D_MODEL + cbase + lc * 8) = o.v;
      }
    } else {
      const int vc0 = gcb - 2048;
      const int h = vc0 >> 6;
      const int bb = row0 >> 11;
      const int s0 = (row0 & (S_LEN - 1)) + wm * 128 + p * 64;
#pragma unroll
      for (int rg = 0; rg < 8; ++rg) {
        const int dk = rg * 8 + lr;
        const bf16x8 vv = ld8(&T[dk][lc * 8]);
        *reinterpret_cast<bf16x8*>(
            VTo + ((size_t)((bb << 4) + h) * 64 + dk) * S_LEN + s0 + lc * 8) = vv;
      }
    }
  }
}

// ---------------------------------------------------------------- attention
// attn6 (best measured): flash, causal, no running max (Q pre-scaled).
// 8 waves x 16 q = 128 q/block, 512 blocks = 2 blocks/CU (the overlap that
// attn8's 1 block/CU lost).  S^T (A=K, B=Q): lane holds q=l15, key=l4*4+r.
__global__ __launch_bounds__(512) void attn6_k(
    const unsigned short* __restrict__ Q, const unsigned short* __restrict__ K,
    const unsigned short* __restrict__ VT, unsigned short* __restrict__ O) {
  const int pair = blockIdx.x;  // 0..7
  const int h = blockIdx.y;
  const int b = blockIdx.z;
  const int tid = threadIdx.x;
  const int w = tid >> 6;       // 0..7
  const int lane = tid & 63;
  const int l15 = lane & 15;
  const int l4 = lane >> 4;

  __shared__ __align__(16) unsigned short Ks[64][72];
  __shared__ __align__(16) unsigned short Vs[64][72];  // Vs[dk][key]
#if !HAVE_MFMA16
  __shared__ __align__(16) unsigned short Ps[8][16][72];
#endif

  const f32x4 fz = {0.f, 0.f, 0.f, 0.f};
  const unsigned short* kbase = K + (size_t)b * S_LEN * D_MODEL + h * D_HEAD;
  const unsigned short* vbase = VT + (size_t)((b << 4) + h) * 64 * S_LEN;

  const int rr = tid >> 3;        // staging row 0..63 (512 thr cover 64x64)
  const int c8 = (tid & 7) * 8;   // staging 8-short chunk

  for (int half = 0; half < 2; ++half) {
    const int qt = half ? (15 - pair) : pair;
    const int qb = qt * 128;
    const int qw0 = qb + w * 16;

    bf16x8 qf[2];
#pragma unroll
    for (int kc = 0; kc < 2; ++kc)
      qf[kc] = ld8(Q + (size_t)(b * S_LEN + qw0 + l15) * D_MODEL +
                   h * D_HEAD + kc * 32 + l4 * 8);

    f32x4 o[4];
#pragma unroll
    for (int d = 0; d < 4; ++d) o[d] = fz;
    float lsum = 0.f;

    const int nkt = qb / 64 + 2;
    // prefetch tile 0
    uint4 kreg = *reinterpret_cast<const uint4*>(kbase + (size_t)rr * D_MODEL + c8);
    uint4 vreg = *reinterpret_cast<const uint4*>(vbase + (size_t)rr * S_LEN + c8);

    for (int kt = 0; kt < nkt; ++kt) {
      const int kb0 = kt * 64;
      *reinterpret_cast<uint4*>(&Ks[rr][c8]) = kreg;
      *reinterpret_cast<uint4*>(&Vs[rr][c8]) = vreg;
      if (kt + 1 < nkt) {  // prefetch next tile; hides behind this tile's math
        const int nb0 = kb0 + 64;
        kreg = *reinterpret_cast<const uint4*>(kbase + (size_t)(nb0 + rr) * D_MODEL + c8);
        vreg = *reinterpret_cast<const uint4*>(vbase + (size_t)rr * S_LEN + nb0 + c8);
      }
      __syncthreads();

      if (kb0 <= qw0 + 15) {
        // ---- S^T = K Q^T : lane holds q=l15, key=kb0+n*16+l4*4+r
        f32x4 s[4];
#pragma unroll
        for (int n = 0; n < 4; ++n) {
          const bf16x8 kf0 = ld8(&Ks[n * 16 + l15][l4 * 8]);
          const bf16x8 kf1 = ld8(&Ks[n * 16 + l15][32 + l4 * 8]);
          f32x4 a0 = __builtin_amdgcn_mfma_f32_16x16x32_bf16(kf0, qf[0], fz, 0, 0, 0);
          s[n] = __builtin_amdgcn_mfma_f32_16x16x32_bf16(kf1, qf[1], a0, 0, 0, 0);
        }
        // ---- exp2 + causal mask + per-lane row-sum + pack to bf16
        bf16x4 pf[4];
        const bool full = (kb0 + 63 <= qw0);
        const int q = qw0 + l15;
        float su = lsum;
#pragma unroll
        for (int n = 0; n < 4; ++n) {
          float e[4];
          if (full) {
#pragma unroll
            for (int r = 0; r < 4; ++r) e[r] = exp2f(s[n][r]);
          } else {
#pragma unroll
            for (int r = 0; r < 4; ++r) {
              const int key = kb0 + n * 16 + l4 * 4 + r;
              const float v = exp2f(s[n][r]);
              e[r] = (key <= q) ? v : 0.f;
            }
          }
          su += (e[0] + e[1]) + (e[2] + e[3]);
          union { unsigned int u[2]; bf16x4 v; } pk;
          pk.u[0] = pkbf(e[0], e[1]);
          pk.u[1] = pkbf(e[2], e[3]);
          pf[n] = pk.v;
        }
        lsum = su;

        // ---- O^T += V^T P^T (P in-register as B-operand)
#if HAVE_MFMA16
#pragma unroll
        for (int d = 0; d < 4; ++d) {
          bf16x4 vfc[4];
#pragma unroll
          for (int c = 0; c < 4; ++c) vfc[c] = ld4(&Vs[d * 16 + l15][c * 16 + l4 * 4]);
#pragma unroll
          for (int c = 0; c < 4; ++c)
            o[d] = __builtin_amdgcn_mfma_f32_16x16x16bf16_1k(vfc[c], pf[c], o[d], 0, 0, 0);
        }
#else
#pragma unroll
        for (int n = 0; n < 4; ++n)
          *reinterpret_cast<bf16x4*>(&Ps[w][l15][n * 16 + l4 * 4]) = pf[n];
        bf16x8 pfr[2];
#pragma unroll
        for (int kc = 0; kc < 2; ++kc)
          pfr[kc] = ld8(&Ps[w][l15][kc * 32 + l4 * 8]);
#pragma unroll
        for (int d = 0; d < 4; ++d) {
          const bf16x8 vf0 = ld8(&Vs[d * 16 + l15][l4 * 8]);
          const bf16x8 vf1 = ld8(&Vs[d * 16 + l15][32 + l4 * 8]);
          o[d] = __builtin_amdgcn_mfma_f32_16x16x32_bf16(vf0, pfr[0], o[d], 0, 0, 0);
          o[d] = __builtin_amdgcn_mfma_f32_16x16x32_bf16(vf1, pfr[1], o[d], 0, 0, 0);
        }
#endif
      }
      __syncthreads();
    }

    // lsum lives per-lane at q=l15; reduce across quads (lane bits 4,5)
    float s = lsum;
    s += __shfl_xor(s, 16);
    s += __shfl_xor(s, 32);
    const float li = 1.0f / s;
    unsigned short* op = O + (size_t)(b * S_LEN + qw0 + l15) * D_MODEL +
                         h * D_HEAD + l4 * 4;
#pragma unroll
    for (int d = 0; d < 4; ++d) {
      union { unsigned int u[2]; uint2 v; } ov;
      ov.u[0] = pkbf(o[d][0] * li, o[d][1] * li);
      ov.u[1] = pkbf(o[d][2] * li, o[d][3] * li);
      *reinterpret_cast<uint2*>(op + d * 16) = ov.v;
    }
  }
}

// ---------------------------------------------------------------- launch
extern "C" void kernel_launch(void* const* d_in, const int* in_sizes, int n_in,
                              void* d_out, int out_size, void* d_ws, size_t ws_size,
                              hipStream_t stream) {
  const float* x  = (const float*)d_in[0];
  const float* Wq = (const float*)d_in[1];
  const float* Wk = (const float*)d_in[2];
  const float* Wv = (const float*)d_in[3];
  const float* Wo = (const float*)d_in[4];
  const int* pos  = (const int*)d_in[5];
  float* out = (float*)d_out;

  char* ws = (char*)d_ws;
  const size_t big = (size_t)M_ROWS * D_MODEL * 2;  // 16 MiB
  const size_t wsz = (size_t)D_MODEL * D_MODEL * 2; // 2 MiB
  unsigned short* xb  = (unsigned short*)(ws + 0 * big);
  unsigned short* Qb  = (unsigned short*)(ws + 1 * big);  // attn out aliases Qb
  unsigned short* Kb  = (unsigned short*)(ws + 2 * big);
  unsigned short* VT  = (unsigned short*)(ws + 3 * big);
  unsigned short* Wqkvt = (unsigned short*)(ws + 4 * big);
  unsigned short* Wot   = (unsigned short*)(ws + 4 * big + 3 * wsz);
  float2* tab = (float2*)d_out;  // free scratch until final projection

  rope_tab_k<<<dim3(S_LEN * 32 / 256), 256, 0, stream>>>(pos, tab);
  cast_k<<<dim3(M_ROWS * D_MODEL / 2048), 256, 0, stream>>>(x, xb);
  wtrans_k<<<dim3(16, 16, 4), 256, 0, stream>>>(
      Wq, Wk, Wv, Wo, Wqkvt, Wqkvt + (size_t)D_MODEL * D_MODEL,
      Wqkvt + 2 * (size_t)D_MODEL * D_MODEL, Wot);
  gemm9_k<<<dim3(M_ROWS / 256, 3 * D_MODEL / 256), 512, 0, stream>>>(
      xb, Wqkvt, Qb, Kb, VT, tab);
  attn6_k<<<dim3(8, N_HEAD, B_N), 512, 0, stream>>>(Qb, Kb, VT, Qb);
  gemm2_k<<<dim3(M_ROWS / 128, D_MODEL / 128), 256, 0, stream>>>(Qb, Wot, out);
}

// Round 8
// 453.174 us; speedup vs baseline: 1.0062x; 1.0062x over previous
//
#include <hip/hip_runtime.h>
#include <hip/hip_bf16.h>

#define B_N 4
#define S_LEN 2048
#define D_MODEL 1024
#define N_HEAD 16
#define D_HEAD 64
#define M_ROWS (B_N * S_LEN) /* 8192 */

typedef short bf16x8 __attribute__((ext_vector_type(8)));
typedef short bf16x4 __attribute__((ext_vector_type(4)));
typedef float f32x4 __attribute__((ext_vector_type(4)));

#if __has_builtin(__builtin_amdgcn_mfma_f32_16x16x16bf16_1k)
#define HAVE_MFMA16 1
#else
#define HAVE_MFMA16 0
#endif

__device__ __forceinline__ unsigned short f2bf(float f) {
  union { float f; unsigned int u; } v; v.f = f;
  unsigned int r = v.u + 0x7FFFu + ((v.u >> 16) & 1u);
  return (unsigned short)(r >> 16);
}
__device__ __forceinline__ float bf2f(unsigned short u) {
  union { unsigned int u; float f; } v; v.u = ((unsigned int)u) << 16;
  return v.f;
}
// packed f32x2 -> bf16x2 (v_cvt_pk_bf16_f32, RNE)
__device__ __forceinline__ unsigned int pkbf(float a, float b) {
  union { __hip_bfloat162 h; unsigned int u; } cv;
  cv.h = __float22bfloat162_rn(make_float2(a, b));
  return cv.u;
}
__device__ __forceinline__ bf16x8 ld8(const unsigned short* p) {
  return *reinterpret_cast<const bf16x8*>(p);
}
__device__ __forceinline__ bf16x4 ld4(const unsigned short* p) {
  return *reinterpret_cast<const bf16x4*>(p);
}
__device__ __forceinline__ void glds16(const unsigned short* g, unsigned short* l) {
  __builtin_amdgcn_global_load_lds(
      (const __attribute__((address_space(1))) unsigned int*)g,
      (__attribute__((address_space(3))) unsigned int*)l, 16, 0, 0);
}

// ---------------------------------------------------------------- rope table
__global__ __launch_bounds__(256) void rope_tab_k(const int* __restrict__ pos,
                                                  float2* __restrict__ tab) {
  const int idx = blockIdx.x * 256 + threadIdx.x;
  const int s = idx >> 5;
  const int i = idx & 31;
  const float inv = exp2f(-(float)i * 0.41524101186092029f);  // log2(1e4)/32
  const float ang = (float)pos[s] * inv;
  tab[idx] = make_float2(cosf(ang), sinf(ang));
}

// ---------------------------------------------------------------- cast x
__global__ __launch_bounds__(256) void cast_k(const float* __restrict__ X,
                                              unsigned short* __restrict__ Y) {
  const size_t i = ((size_t)blockIdx.x * 256 + threadIdx.x) * 8;
  const float4 a = *reinterpret_cast<const float4*>(X + i);
  const float4 b = *reinterpret_cast<const float4*>(X + i + 4);
  union { unsigned int u[4]; uint4 v; } o;
  o.u[0] = pkbf(a.x, a.y); o.u[1] = pkbf(a.z, a.w);
  o.u[2] = pkbf(b.x, b.y); o.u[3] = pkbf(b.z, b.w);
  *reinterpret_cast<uint4*>(Y + i) = o.v;
}

// ---------------------------------------------------------------- transpose
__global__ __launch_bounds__(256) void wtrans_k(
    const float* __restrict__ W0, const float* __restrict__ W1,
    const float* __restrict__ W2, const float* __restrict__ W3,
    unsigned short* __restrict__ T0, unsigned short* __restrict__ T1,
    unsigned short* __restrict__ T2, unsigned short* __restrict__ T3) {
  const int z = blockIdx.z;
  const float* __restrict__ W = (z == 0) ? W0 : (z == 1) ? W1 : (z == 2) ? W2 : W3;
  unsigned short* __restrict__ T = (z == 0) ? T0 : (z == 1) ? T1 : (z == 2) ? T2 : T3;
  __shared__ __align__(16) unsigned short tile[64][72];
  const int kb = blockIdx.x * 64;
  const int nb = blockIdx.y * 64;
#pragma unroll
  for (int it = 0; it < 2; ++it) {
    const int chunk = it * 256 + threadIdx.x;
    const int r = chunk >> 3;
    const int c8 = (chunk & 7) * 8;
    const float* src = W + (size_t)(kb + r) * D_MODEL + nb + c8;
    const float4 a = *reinterpret_cast<const float4*>(src);
    const float4 b = *reinterpret_cast<const float4*>(src + 4);
    union { unsigned int u[4]; uint4 v; } o;
    o.u[0] = pkbf(a.x, a.y); o.u[1] = pkbf(a.z, a.w);
    o.u[2] = pkbf(b.x, b.y); o.u[3] = pkbf(b.z, b.w);
    *reinterpret_cast<uint4*>(&tile[r][c8]) = o.v;
  }
  __syncthreads();
#pragma unroll
  for (int it = 0; it < 2; ++it) {
    const int chunk = it * 256 + threadIdx.x;
    const int n = chunk >> 3;
    const int k8 = (chunk & 7) * 8;
    __align__(16) unsigned short vals[8];
#pragma unroll
    for (int j = 0; j < 8; ++j) vals[j] = tile[k8 + j][n];
    *reinterpret_cast<uint4*>(T + (size_t)(nb + n) * D_MODEL + kb + k8) =
        *reinterpret_cast<const uint4*>(vals);
  }
}

// ---------------------------------------------------------------- GEMM (proj)
// 128x128 tile, BK=32, global_load_lds staging, 4 waves x (4x4 frags).
__global__ __launch_bounds__(256) void gemm2_k(
    const unsigned short* __restrict__ A, const unsigned short* __restrict__ W,
    float* __restrict__ OF) {
  __shared__ __align__(16) unsigned short smem[4][64][68];
  unsigned short* As = &smem[0][0][0];
  unsigned short* Bs = As + 128 * 32;

  const int tid = threadIdx.x;
  const int lane = tid & 63;
  const int w = tid >> 6;
  const int l15 = lane & 15;
  const int l4 = lane >> 4;

  const int row0 = blockIdx.x * 128;
  const int col0 = blockIdx.y * 128;

  const int srow = w * 32 + (lane >> 2);
  const int scol = (lane & 3) * 8;
  const unsigned short* ga = A + (size_t)(row0 + srow) * D_MODEL + scol;
  const unsigned short* gb = W + (size_t)(col0 + srow) * D_MODEL + scol;
  unsigned short* la = &As[(w * 32) * 32];
  unsigned short* lb = &Bs[(w * 32) * 32];

  const int wrow = (w & 1) * 64;
  const int wcol = (w >> 1) * 64;

  f32x4 acc[4][4];
  const f32x4 fz = {0.f, 0.f, 0.f, 0.f};
#pragma unroll
  for (int m = 0; m < 4; ++m)
#pragma unroll
    for (int n = 0; n < 4; ++n) acc[m][n] = fz;

  for (int kb = 0; kb < D_MODEL; kb += 32) {
    glds16(ga + kb, la);
    glds16(ga + 16 * D_MODEL + kb, la + 16 * 32);
    glds16(gb + kb, lb);
    glds16(gb + 16 * D_MODEL + kb, lb + 16 * 32);
    __syncthreads();
    bf16x8 af[4], bfr[4];
#pragma unroll
    for (int m = 0; m < 4; ++m) af[m] = ld8(&As[(wrow + m * 16 + l15) * 32 + l4 * 8]);
#pragma unroll
    for (int n = 0; n < 4; ++n) bfr[n] = ld8(&Bs[(wcol + n * 16 + l15) * 32 + l4 * 8]);
#pragma unroll
    for (int m = 0; m < 4; ++m)
#pragma unroll
      for (int n = 0; n < 4; ++n)
        acc[m][n] = __builtin_amdgcn_mfma_f32_16x16x32_bf16(af[m], bfr[n], acc[m][n], 0, 0, 0);
    __syncthreads();
  }

#pragma unroll
  for (int n = 0; n < 4; ++n) {
    const int gcol = col0 + wcol + n * 16 + l15;
#pragma unroll
    for (int m = 0; m < 4; ++m)
#pragma unroll
      for (int r = 0; r < 4; ++r)
        OF[(size_t)(row0 + wrow + m * 16 + l4 * 4 + r) * D_MODEL + gcol] = acc[m][n][r];
  }
}

// ---------------------------------------------------------------- QKV GEMM
// m201-template port: 256x256 tile, BK=64, 8 waves (2M x 4N, wave-tile
// 128x64), LDS 128 KiB [slot2][A/B][half2][128x64].  Per iteration (K-tiles
// u=2i slot0, v=2i+1 slot1): 8 phases, each = {12 swizzled ds_read_b128 (one
// C-quadrant) | stage 1 half-tile (2 glds) | barrier | setprio(1) 16 MFMA
// setprio(0) | [vmcnt(2) at P3/P7] | barrier}.
// Stage schedule (ledger verified, round 7: race-free, 0 bank conflicts):
// P0:B0(v) P1:A1(v) P2:B1(v) P3:A0(u+2) P4:B0(u+2) P5:A1(u+2) P6:B1(u+2)
// P7:A0(v+2).  vmcnt(2)+barrier at P3/P7 guard the next 4 phases' slot.
// vmcnt(0) only at i=7.  Swizzle: chunk ^= (row&7) on stage source AND read.
// launch_bounds(512,2): the attribute under which this exact register load
// (acc[8][4] + 12 operand frags) allocates acc to AGPRs with NO spill
// (round-1 evidence: VGPR 112, WRITE normal); (512,1) spilled (round 7).
__global__ __launch_bounds__(512, 2) void gemm9_k(
    const unsigned short* __restrict__ A, const unsigned short* __restrict__ W,
    unsigned short* __restrict__ Qo, unsigned short* __restrict__ Ko,
    unsigned short* __restrict__ VTo, const float2* __restrict__ tab) {
  __shared__ __align__(16) unsigned short smem[2][2][2][128 * 64];  // 128 KiB

  const int tid = threadIdx.x;
  const int lane = tid & 63;
  const int w = tid >> 6;   // 0..7
  const int l15 = lane & 15;
  const int l4 = lane >> 4;
  const int wm = w >> 2;    // 0..1 : 128-row M-half
  const int wn = w & 3;     // 0..3 : 64-col N-quarter
  const int hb = wn >> 1;   // B half this wave reads
  const int rbb = (wn & 1) * 64;  // B row base within half

  const int row0 = blockIdx.x * 256;
  const int col0 = blockIdx.y * 256;

  // Staging: wave w, call j covers rows w*16+j*8+(lane>>3) of a 128-row half;
  // global chunk pre-swizzled (lane&7)^(row&7); LDS dest linear.
  const int srow8 = lane >> 3;            // 0..7 == row&7 of staged row
  const int schunk = (lane & 7) ^ srow8;  // swizzled 16B chunk
  const unsigned short* gA = A + (size_t)(row0 + w * 16 + srow8) * D_MODEL + schunk * 8;
  const unsigned short* gB = W + (size_t)(col0 + w * 16 + srow8) * D_MODEL + schunk * 8;

  // ds_read chunk offsets (shorts) for the two K-halves; row&7 == l15&7.
  const int swz = l15 & 7;
  const int kc0 = (l4 ^ swz) * 8;
  const int kc1 = ((l4 + 4) ^ swz) * 8;

  f32x4 acc[8][4];
  const f32x4 fz = {0.f, 0.f, 0.f, 0.f};
#pragma unroll
  for (int m = 0; m < 8; ++m)
#pragma unroll
    for (int n = 0; n < 4; ++n) acc[m][n] = fz;

  // stage one half-tile: AB 0=A 1=B, half HA, K-tile T, into slot SL
#define STG(SL, AB, HA, T)                                                     \
  do {                                                                         \
    const unsigned short* g_ =                                                 \
        ((AB) ? gB : gA) + (size_t)(HA) * 128 * D_MODEL + (size_t)(T) * 64;    \
    unsigned short* d_ = &smem[SL][AB][HA][w * 1024];                          \
    glds16(g_, d_);                                                            \
    glds16(g_ + 8 * D_MODEL, d_ + 512);                                        \
  } while (0)

  // one phase: quadrant (QM,QN) of slot SL; STGX issued pre-barrier; TAILW
  // (vmcnt) sits between setprio(0) and the trailing barrier.
#define PH(SL, QM, QN, STGX, TAILW)                                            \
  do {                                                                         \
    bf16x8 af_[4][2], bf_[2][2];                                               \
    _Pragma("unroll") for (int mi = 0; mi < 4; ++mi) {                         \
      const int ra_ = ((QM) * 64 + mi * 16 + l15) * 64;                        \
      af_[mi][0] = ld8(&smem[SL][0][wm][ra_ + kc0]);                           \
      af_[mi][1] = ld8(&smem[SL][0][wm][ra_ + kc1]);                           \
    }                                                                          \
    _Pragma("unroll") for (int ni = 0; ni < 2; ++ni) {                         \
      const int rb_ = (rbb + (QN) * 32 + ni * 16 + l15) * 64;                  \
      bf_[ni][0] = ld8(&smem[SL][1][hb][rb_ + kc0]);                           \
      bf_[ni][1] = ld8(&smem[SL][1][hb][rb_ + kc1]);                           \
    }                                                                          \
    STGX;                                                                      \
    __builtin_amdgcn_s_barrier();                                              \
    __builtin_amdgcn_s_setprio(1);                                             \
    _Pragma("unroll") for (int mi = 0; mi < 4; ++mi)                           \
      _Pragma("unroll") for (int ni = 0; ni < 2; ++ni) {                       \
        acc[(QM) * 4 + mi][(QN) * 2 + ni] =                                    \
            __builtin_amdgcn_mfma_f32_16x16x32_bf16(                           \
                af_[mi][0], bf_[ni][0], acc[(QM) * 4 + mi][(QN) * 2 + ni],     \
                0, 0, 0);                                                      \
        acc[(QM) * 4 + mi][(QN) * 2 + ni] =                                    \
            __builtin_amdgcn_mfma_f32_16x16x32_bf16(                           \
                af_[mi][1], bf_[ni][1], acc[(QM) * 4 + mi][(QN) * 2 + ni],     \
                0, 0, 0);                                                      \
      }                                                                        \
    __builtin_amdgcn_s_setprio(0);                                             \
    TAILW;                                                                     \
    __builtin_amdgcn_s_barrier();                                              \
  } while (0)

#define VM2 asm volatile("s_waitcnt vmcnt(2)" ::: "memory")
#define VM0 asm volatile("s_waitcnt vmcnt(0)" ::: "memory")
#define NOP ((void)0)

  // Prologue: tile0 (all 4 halves) + A0 of tile1 = 10 loads/thread
  STG(0, 0, 0, 0); STG(0, 1, 0, 0); STG(0, 0, 1, 0); STG(0, 1, 1, 0);
  STG(1, 0, 0, 1);
  VM2;  // tile0 fully landed (A0(1) may fly)
  __builtin_amdgcn_s_barrier();

  for (int i = 0; i < 8; ++i) {
    const int v = 2 * i + 1;
    const int u2 = 2 * i + 2;
    if (i < 7) {
      PH(0, 0, 0, STG(1, 1, 0, v), NOP);   // P0: stage B0(v)
      PH(0, 0, 1, STG(1, 0, 1, v), NOP);   // P1: stage A1(v)
      PH(0, 1, 0, STG(1, 1, 1, v), NOP);   // P2: stage B1(v)
      PH(0, 1, 1, STG(0, 0, 0, u2), VM2);  // P3: stage A0(u+2); guard v
      PH(1, 0, 0, STG(0, 1, 0, u2), NOP);  // P4: stage B0(u+2)
      PH(1, 0, 1, STG(0, 0, 1, u2), NOP);  // P5: stage A1(u+2)
      PH(1, 1, 0, STG(0, 1, 1, u2), NOP);  // P6: stage B1(u+2)
      PH(1, 1, 1, STG(1, 0, 0, u2 + 1), VM2);  // P7: stage A0(v+2); guard u+2
    } else {
      PH(0, 0, 0, STG(1, 1, 0, v), NOP);
      PH(0, 0, 1, STG(1, 0, 1, v), NOP);
      PH(0, 1, 0, STG(1, 1, 1, v), NOP);
      PH(0, 1, 1, NOP, VM0);               // final drain
      PH(1, 0, 0, NOP, NOP);
      PH(1, 0, 1, NOP, NOP);
      PH(1, 1, 0, NOP, NOP);
      PH(1, 1, 1, NOP, NOP);
    }
  }
#undef STG
#undef PH
#undef VM2
#undef VM0
#undef NOP

  // ---------------- epilogue: rope (Q/K) or transpose (V); wave does its
  // 128x64 output in 2 passes of 64 rows through wave-private LDS.
  unsigned short(*T)[68] =
      (unsigned short(*)[68])((unsigned short*)smem + w * 4352);  // 64x68
  const int gcb = col0 + wn * 64;  // 64-aligned -> one head per wave
  const bool isV = (gcb >= 2048);
  const int lr = lane >> 3;
  const int lc = lane & 7;

#pragma unroll
  for (int p = 0; p < 2; ++p) {
    if (!isV) {
#pragma unroll
      for (int mi = 0; mi < 4; ++mi)
#pragma unroll
        for (int n = 0; n < 4; ++n)
#pragma unroll
          for (int r = 0; r < 4; ++r)
            T[mi * 16 + l4 * 4 + r][n * 16 + l15] = f2bf(acc[p * 4 + mi][n][r]);
    } else {
#pragma unroll
      for (int mi = 0; mi < 4; ++mi)
#pragma unroll
        for (int n = 0; n < 4; ++n)
#pragma unroll
          for (int r = 0; r < 4; ++r)
            T[n * 16 + l15][mi * 16 + l4 * 4 + r] = f2bf(acc[p * 4 + mi][n][r]);
    }
    if (!isV) {
      const bool isQ = (gcb < 1024);
      unsigned short* O = isQ ? Qo : Ko;
      // fold softmax scale into Q: 1/sqrt(64) * log2(e)
      const float qs = isQ ? 0.18033688011112042f : 1.0f;
      const int cbase = gcb & 1023;
#pragma unroll
      for (int rg = 0; rg < 8; ++rg) {
        const int trow = rg * 8 + lr;
        const int grow = row0 + wm * 128 + p * 64 + trow;
        const int s = grow & (S_LEN - 1);
        const bf16x8 vv = ld8(&T[trow][lc * 8]);
        const float4 tA = *reinterpret_cast<const float4*>(&tab[s * 32 + lc * 4]);
        const float4 tB = *reinterpret_cast<const float4*>(&tab[s * 32 + lc * 4 + 2]);
        float x[8];
#pragma unroll
        for (int j = 0; j < 8; ++j) x[j] = bf2f((unsigned short)vv[j]);
        union { unsigned int u[4]; uint4 v; } o;
        o.u[0] = pkbf((x[0] * tA.x - x[1] * tA.y) * qs, (x[0] * tA.y + x[1] * tA.x) * qs);
        o.u[1] = pkbf((x[2] * tA.z - x[3] * tA.w) * qs, (x[2] * tA.w + x[3] * tA.z) * qs);
        o.u[2] = pkbf((x[4] * tB.x - x[5] * tB.y) * qs, (x[4] * tB.y + x[5] * tB.x) * qs);
        o.u[3] = pkbf((x[6] * tB.z - x[7] * tB.w) * qs, (x[6] * tB.w + x[7] * tB.z) * qs);
        *reinterpret_cast<uint4*>(O + (size_t)grow * D_MODEL + cbase + lc * 8) = o.v;
      }
    } else {
      const int vc0 = gcb - 2048;
      const int h = vc0 >> 6;
      const int bb = row0 >> 11;
      const int s0 = (row0 & (S_LEN - 1)) + wm * 128 + p * 64;
#pragma unroll
      for (int rg = 0; rg < 8; ++rg) {
        const int dk = rg * 8 + lr;
        const bf16x8 vv = ld8(&T[dk][lc * 8]);
        *reinterpret_cast<bf16x8*>(
            VTo + ((size_t)((bb << 4) + h) * 64 + dk) * S_LEN + s0 + lc * 8) = vv;
      }
    }
  }
}

// ---------------------------------------------------------------- attention
// attn6 (best measured): flash, causal, no running max (Q pre-scaled).
// 8 waves x 16 q = 128 q/block, 512 blocks = 2 blocks/CU.
// S^T (A=K, B=Q): lane holds q=l15, key=l4*4+r.
__global__ __launch_bounds__(512) void attn6_k(
    const unsigned short* __restrict__ Q, const unsigned short* __restrict__ K,
    const unsigned short* __restrict__ VT, unsigned short* __restrict__ O) {
  const int pair = blockIdx.x;  // 0..7
  const int h = blockIdx.y;
  const int b = blockIdx.z;
  const int tid = threadIdx.x;
  const int w = tid >> 6;       // 0..7
  const int lane = tid & 63;
  const int l15 = lane & 15;
  const int l4 = lane >> 4;

  __shared__ __align__(16) unsigned short Ks[64][72];
  __shared__ __align__(16) unsigned short Vs[64][72];  // Vs[dk][key]
#if !HAVE_MFMA16
  __shared__ __align__(16) unsigned short Ps[8][16][72];
#endif

  const f32x4 fz = {0.f, 0.f, 0.f, 0.f};
  const unsigned short* kbase = K + (size_t)b * S_LEN * D_MODEL + h * D_HEAD;
  const unsigned short* vbase = VT + (size_t)((b << 4) + h) * 64 * S_LEN;

  const int rr = tid >> 3;        // staging row 0..63 (512 thr cover 64x64)
  const int c8 = (tid & 7) * 8;   // staging 8-short chunk

  for (int half = 0; half < 2; ++half) {
    const int qt = half ? (15 - pair) : pair;
    const int qb = qt * 128;
    const int qw0 = qb + w * 16;

    bf16x8 qf[2];
#pragma unroll
    for (int kc = 0; kc < 2; ++kc)
      qf[kc] = ld8(Q + (size_t)(b * S_LEN + qw0 + l15) * D_MODEL +
                   h * D_HEAD + kc * 32 + l4 * 8);

    f32x4 o[4];
#pragma unroll
    for (int d = 0; d < 4; ++d) o[d] = fz;
    float lsum = 0.f;

    const int nkt = qb / 64 + 2;
    // prefetch tile 0
    uint4 kreg = *reinterpret_cast<const uint4*>(kbase + (size_t)rr * D_MODEL + c8);
    uint4 vreg = *reinterpret_cast<const uint4*>(vbase + (size_t)rr * S_LEN + c8);

    for (int kt = 0; kt < nkt; ++kt) {
      const int kb0 = kt * 64;
      *reinterpret_cast<uint4*>(&Ks[rr][c8]) = kreg;
      *reinterpret_cast<uint4*>(&Vs[rr][c8]) = vreg;
      if (kt + 1 < nkt) {  // prefetch next tile; hides behind this tile's math
        const int nb0 = kb0 + 64;
        kreg = *reinterpret_cast<const uint4*>(kbase + (size_t)(nb0 + rr) * D_MODEL + c8);
        vreg = *reinterpret_cast<const uint4*>(vbase + (size_t)rr * S_LEN + nb0 + c8);
      }
      __syncthreads();

      if (kb0 <= qw0 + 15) {
        // ---- S^T = K Q^T : lane holds q=l15, key=kb0+n*16+l4*4+r
        f32x4 s[4];
#pragma unroll
        for (int n = 0; n < 4; ++n) {
          const bf16x8 kf0 = ld8(&Ks[n * 16 + l15][l4 * 8]);
          const bf16x8 kf1 = ld8(&Ks[n * 16 + l15][32 + l4 * 8]);
          f32x4 a0 = __builtin_amdgcn_mfma_f32_16x16x32_bf16(kf0, qf[0], fz, 0, 0, 0);
          s[n] = __builtin_amdgcn_mfma_f32_16x16x32_bf16(kf1, qf[1], a0, 0, 0, 0);
        }
        // ---- exp2 + causal mask + per-lane row-sum + pack to bf16
        bf16x4 pf[4];
        const bool full = (kb0 + 63 <= qw0);
        const int q = qw0 + l15;
        float su = lsum;
#pragma unroll
        for (int n = 0; n < 4; ++n) {
          float e[4];
          if (full) {
#pragma unroll
            for (int r = 0; r < 4; ++r) e[r] = exp2f(s[n][r]);
          } else {
#pragma unroll
            for (int r = 0; r < 4; ++r) {
              const int key = kb0 + n * 16 + l4 * 4 + r;
              const float v = exp2f(s[n][r]);
              e[r] = (key <= q) ? v : 0.f;
            }
          }
          su += (e[0] + e[1]) + (e[2] + e[3]);
          union { unsigned int u[2]; bf16x4 v; } pk;
          pk.u[0] = pkbf(e[0], e[1]);
          pk.u[1] = pkbf(e[2], e[3]);
          pf[n] = pk.v;
        }
        lsum = su;

        // ---- O^T += V^T P^T (P in-register as B-operand)
#if HAVE_MFMA16
#pragma unroll
        for (int d = 0; d < 4; ++d) {
          bf16x4 vfc[4];
#pragma unroll
          for (int c = 0; c < 4; ++c) vfc[c] = ld4(&Vs[d * 16 + l15][c * 16 + l4 * 4]);
#pragma unroll
          for (int c = 0; c < 4; ++c)
            o[d] = __builtin_amdgcn_mfma_f32_16x16x16bf16_1k(vfc[c], pf[c], o[d], 0, 0, 0);
        }
#else
#pragma unroll
        for (int n = 0; n < 4; ++n)
          *reinterpret_cast<bf16x4*>(&Ps[w][l15][n * 16 + l4 * 4]) = pf[n];
        bf16x8 pfr[2];
#pragma unroll
        for (int kc = 0; kc < 2; ++kc)
          pfr[kc] = ld8(&Ps[w][l15][kc * 32 + l4 * 8]);
#pragma unroll
        for (int d = 0; d < 4; ++d) {
          const bf16x8 vf0 = ld8(&Vs[d * 16 + l15][l4 * 8]);
          const bf16x8 vf1 = ld8(&Vs[d * 16 + l15][32 + l4 * 8]);
          o[d] = __builtin_amdgcn_mfma_f32_16x16x32_bf16(vf0, pfr[0], o[d], 0, 0, 0);
          o[d] = __builtin_amdgcn_mfma_f32_16x16x32_bf16(vf1, pfr[1], o[d], 0, 0, 0);
        }
#endif
      }
      __syncthreads();
    }

    // lsum lives per-lane at q=l15; reduce across quads (lane bits 4,5)
    float s = lsum;
    s += __shfl_xor(s, 16);
    s += __shfl_xor(s, 32);
    const float li = 1.0f / s;
    unsigned short* op = O + (size_t)(b * S_LEN + qw0 + l15) * D_MODEL +
                         h * D_HEAD + l4 * 4;
#pragma unroll
    for (int d = 0; d < 4; ++d) {
      union { unsigned int u[2]; uint2 v; } ov;
      ov.u[0] = pkbf(o[d][0] * li, o[d][1] * li);
      ov.u[1] = pkbf(o[d][2] * li, o[d][3] * li);
      *reinterpret_cast<uint2*>(op + d * 16) = ov.v;
    }
  }
}

// ---------------------------------------------------------------- launch
extern "C" void kernel_launch(void* const* d_in, const int* in_sizes, int n_in,
                              void* d_out, int out_size, void* d_ws, size_t ws_size,
                              hipStream_t stream) {
  const float* x  = (const float*)d_in[0];
  const float* Wq = (const float*)d_in[1];
  const float* Wk = (const float*)d_in[2];
  const float* Wv = (const float*)d_in[3];
  const float* Wo = (const float*)d_in[4];
  const int* pos  = (const int*)d_in[5];
  float* out = (float*)d_out;

  char* ws = (char*)d_ws;
  const size_t big = (size_t)M_ROWS * D_MODEL * 2;  // 16 MiB
  const size_t wsz = (size_t)D_MODEL * D_MODEL * 2; // 2 MiB
  unsigned short* xb  = (unsigned short*)(ws + 0 * big);
  unsigned short* Qb  = (unsigned short*)(ws + 1 * big);  // attn out aliases Qb
  unsigned short* Kb  = (unsigned short*)(ws + 2 * big);
  unsigned short* VT  = (unsigned short*)(ws + 3 * big);
  unsigned short* Wqkvt = (unsigned short*)(ws + 4 * big);
  unsigned short* Wot   = (unsigned short*)(ws + 4 * big + 3 * wsz);
  float2* tab = (float2*)d_out;  // free scratch until final projection

  rope_tab_k<<<dim3(S_LEN * 32 / 256), 256, 0, stream>>>(pos, tab);
  cast_k<<<dim3(M_ROWS * D_MODEL / 2048), 256, 0, stream>>>(x, xb);
  wtrans_k<<<dim3(16, 16, 4), 256, 0, stream>>>(
      Wq, Wk, Wv, Wo, Wqkvt, Wqkvt + (size_t)D_MODEL * D_MODEL,
      Wqkvt + 2 * (size_t)D_MODEL * D_MODEL, Wot);
  gemm9_k<<<dim3(M_ROWS / 256, 3 * D_MODEL / 256), 512, 0, stream>>>(
      xb, Wqkvt, Qb, Kb, VT, tab);
  attn6_k<<<dim3(8, N_HEAD, B_N), 512, 0, stream>>>(Qb, Kb, VT, Qb);
  gemm2_k<<<dim3(M_ROWS / 128, D_MODEL / 128), 256, 0, stream>>>(Qb, Wot, out);
}

// Round 9
// 264.589 us; speedup vs baseline: 1.7233x; 1.7128x over previous
//
#include <hip/hip_runtime.h>
#include <hip/hip_bf16.h>

#define B_N 4
#define S_LEN 2048
#define D_MODEL 1024
#define N_HEAD 16
#define D_HEAD 64
#define M_ROWS (B_N * S_LEN) /* 8192 */

typedef short bf16x8 __attribute__((ext_vector_type(8)));
typedef short bf16x4 __attribute__((ext_vector_type(4)));
typedef float f32x4 __attribute__((ext_vector_type(4)));

#if __has_builtin(__builtin_amdgcn_mfma_f32_16x16x16bf16_1k)
#define HAVE_MFMA16 1
#else
#define HAVE_MFMA16 0
#endif

__device__ __forceinline__ unsigned short f2bf(float f) {
  union { float f; unsigned int u; } v; v.f = f;
  unsigned int r = v.u + 0x7FFFu + ((v.u >> 16) & 1u);
  return (unsigned short)(r >> 16);
}
__device__ __forceinline__ float bf2f(unsigned short u) {
  union { unsigned int u; float f; } v; v.u = ((unsigned int)u) << 16;
  return v.f;
}
// packed f32x2 -> bf16x2 (v_cvt_pk_bf16_f32, RNE)
__device__ __forceinline__ unsigned int pkbf(float a, float b) {
  union { __hip_bfloat162 h; unsigned int u; } cv;
  cv.h = __float22bfloat162_rn(make_float2(a, b));
  return cv.u;
}
__device__ __forceinline__ bf16x8 ld8(const unsigned short* p) {
  return *reinterpret_cast<const bf16x8*>(p);
}
__device__ __forceinline__ bf16x4 ld4(const unsigned short* p) {
  return *reinterpret_cast<const bf16x4*>(p);
}
__device__ __forceinline__ void glds16(const unsigned short* g, unsigned short* l) {
  __builtin_amdgcn_global_load_lds(
      (const __attribute__((address_space(1))) unsigned int*)g,
      (__attribute__((address_space(3))) unsigned int*)l, 16, 0, 0);
}

// ---------------------------------------------------------------- rope table
__global__ __launch_bounds__(256) void rope_tab_k(const int* __restrict__ pos,
                                                  float2* __restrict__ tab) {
  const int idx = blockIdx.x * 256 + threadIdx.x;
  const int s = idx >> 5;
  const int i = idx & 31;
  const float inv = exp2f(-(float)i * 0.41524101186092029f);  // log2(1e4)/32
  const float ang = (float)pos[s] * inv;
  tab[idx] = make_float2(cosf(ang), sinf(ang));
}

// ---------------------------------------------------------------- cast x
__global__ __launch_bounds__(256) void cast_k(const float* __restrict__ X,
                                              unsigned short* __restrict__ Y) {
  const size_t i = ((size_t)blockIdx.x * 256 + threadIdx.x) * 8;
  const float4 a = *reinterpret_cast<const float4*>(X + i);
  const float4 b = *reinterpret_cast<const float4*>(X + i + 4);
  union { unsigned int u[4]; uint4 v; } o;
  o.u[0] = pkbf(a.x, a.y); o.u[1] = pkbf(a.z, a.w);
  o.u[2] = pkbf(b.x, b.y); o.u[3] = pkbf(b.z, b.w);
  *reinterpret_cast<uint4*>(Y + i) = o.v;
}

// ---------------------------------------------------------------- transpose
__global__ __launch_bounds__(256) void wtrans_k(
    const float* __restrict__ W0, const float* __restrict__ W1,
    const float* __restrict__ W2, const float* __restrict__ W3,
    unsigned short* __restrict__ T0, unsigned short* __restrict__ T1,
    unsigned short* __restrict__ T2, unsigned short* __restrict__ T3) {
  const int z = blockIdx.z;
  const float* __restrict__ W = (z == 0) ? W0 : (z == 1) ? W1 : (z == 2) ? W2 : W3;
  unsigned short* __restrict__ T = (z == 0) ? T0 : (z == 1) ? T1 : (z == 2) ? T2 : T3;
  __shared__ __align__(16) unsigned short tile[64][72];
  const int kb = blockIdx.x * 64;
  const int nb = blockIdx.y * 64;
#pragma unroll
  for (int it = 0; it < 2; ++it) {
    const int chunk = it * 256 + threadIdx.x;
    const int r = chunk >> 3;
    const int c8 = (chunk & 7) * 8;
    const float* src = W + (size_t)(kb + r) * D_MODEL + nb + c8;
    const float4 a = *reinterpret_cast<const float4*>(src);
    const float4 b = *reinterpret_cast<const float4*>(src + 4);
    union { unsigned int u[4]; uint4 v; } o;
    o.u[0] = pkbf(a.x, a.y); o.u[1] = pkbf(a.z, a.w);
    o.u[2] = pkbf(b.x, b.y); o.u[3] = pkbf(b.z, b.w);
    *reinterpret_cast<uint4*>(&tile[r][c8]) = o.v;
  }
  __syncthreads();
#pragma unroll
  for (int it = 0; it < 2; ++it) {
    const int chunk = it * 256 + threadIdx.x;
    const int n = chunk >> 3;
    const int k8 = (chunk & 7) * 8;
    __align__(16) unsigned short vals[8];
#pragma unroll
    for (int j = 0; j < 8; ++j) vals[j] = tile[k8 + j][n];
    *reinterpret_cast<uint4*>(T + (size_t)(nb + n) * D_MODEL + kb + k8) =
        *reinterpret_cast<const uint4*>(vals);
  }
}

// ---------------------------------------------------------------- GEMM (proj)
// 128x128 tile, BK=32, global_load_lds staging, 4 waves x (4x4 frags).
__global__ __launch_bounds__(256) void gemm2_k(
    const unsigned short* __restrict__ A, const unsigned short* __restrict__ W,
    float* __restrict__ OF) {
  __shared__ __align__(16) unsigned short smem[4][64][68];
  unsigned short* As = &smem[0][0][0];
  unsigned short* Bs = As + 128 * 32;

  const int tid = threadIdx.x;
  const int lane = tid & 63;
  const int w = tid >> 6;
  const int l15 = lane & 15;
  const int l4 = lane >> 4;

  const int row0 = blockIdx.x * 128;
  const int col0 = blockIdx.y * 128;

  const int srow = w * 32 + (lane >> 2);
  const int scol = (lane & 3) * 8;
  const unsigned short* ga = A + (size_t)(row0 + srow) * D_MODEL + scol;
  const unsigned short* gb = W + (size_t)(col0 + srow) * D_MODEL + scol;
  unsigned short* la = &As[(w * 32) * 32];
  unsigned short* lb = &Bs[(w * 32) * 32];

  const int wrow = (w & 1) * 64;
  const int wcol = (w >> 1) * 64;

  f32x4 acc[4][4];
  const f32x4 fz = {0.f, 0.f, 0.f, 0.f};
#pragma unroll
  for (int m = 0; m < 4; ++m)
#pragma unroll
    for (int n = 0; n < 4; ++n) acc[m][n] = fz;

  for (int kb = 0; kb < D_MODEL; kb += 32) {
    glds16(ga + kb, la);
    glds16(ga + 16 * D_MODEL + kb, la + 16 * 32);
    glds16(gb + kb, lb);
    glds16(gb + 16 * D_MODEL + kb, lb + 16 * 32);
    __syncthreads();
    bf16x8 af[4], bfr[4];
#pragma unroll
    for (int m = 0; m < 4; ++m) af[m] = ld8(&As[(wrow + m * 16 + l15) * 32 + l4 * 8]);
#pragma unroll
    for (int n = 0; n < 4; ++n) bfr[n] = ld8(&Bs[(wcol + n * 16 + l15) * 32 + l4 * 8]);
#pragma unroll
    for (int m = 0; m < 4; ++m)
#pragma unroll
      for (int n = 0; n < 4; ++n)
        acc[m][n] = __builtin_amdgcn_mfma_f32_16x16x32_bf16(af[m], bfr[n], acc[m][n], 0, 0, 0);
    __syncthreads();
  }

#pragma unroll
  for (int n = 0; n < 4; ++n) {
    const int gcol = col0 + wcol + n * 16 + l15;
#pragma unroll
    for (int m = 0; m < 4; ++m)
#pragma unroll
      for (int r = 0; r < 4; ++r)
        OF[(size_t)(row0 + wrow + m * 16 + l4 * 4 + r) * D_MODEL + gcol] = acc[m][n][r];
  }
}

// ---------------------------------------------------------------- QKV GEMM
// 128x256 tile, BK=64, 8 waves (2M x 4N), grid 64x12 = 768 blocks = 3.0 exact
// rounds at 1 block/CU (no tail).  Per K-tile: 2 phases (one per K-half), each
// {8x ds_read_b128 (swizzled) | stage burst | barrier | setprio(1) 16x MFMA
//  setprio(0) | barrier} -- full-hold fragments, zero redundant LDS reads.
// LDS: 3 slots; tile t reads slot t%3 while staging t+2 into (t+2)%3.
// Counted vmcnt(6) per tile head; vmcnt(0) only at tile 15.
// Bank swizzle: physical 16B chunk = logical ^ (row&7) on BOTH sides.
// (Round-4 verified: ~83us, no spill.  The 8-phase 256x256 port (r7/r8)
// scratch-spilled acc (553MB writes) regardless of launch_bounds -- reverted.)
__global__ __launch_bounds__(512, 1) void gemm8_k(
    const unsigned short* __restrict__ A, const unsigned short* __restrict__ W,
    unsigned short* __restrict__ Qo, unsigned short* __restrict__ Ko,
    unsigned short* __restrict__ VTo, const float2* __restrict__ tab) {
  __shared__ __align__(16) unsigned short smem[3][384 * 64];  // 144 KiB

  const int tid = threadIdx.x;
  const int lane = tid & 63;
  const int w = tid >> 6;   // 0..7
  const int l15 = lane & 15;
  const int l4 = lane >> 4;
  const int wm = w >> 2;    // 0..1 : 64-row half
  const int wn = w & 3;     // 0..3 : 64-col quarter

  const int row0 = blockIdx.x * 128;
  const int col0 = blockIdx.y * 256;

  const int srow = lane >> 3;            // 0..7  == row&7 of the staged row
  const int schunk = (lane & 7) ^ srow;  // swizzled 16B chunk in the row
  const unsigned short* gA = A + (size_t)(row0 + w * 8 + srow) * D_MODEL + schunk * 8;
  const unsigned short* gB = W + (size_t)(col0 + w * 8 + srow) * D_MODEL + schunk * 8;

  const int swz = l15 & 7;
  const int kc0 = ((l4) ^ swz) * 8;
  const int kc1 = ((l4 + 4) ^ swz) * 8;

  f32x4 acc[4][4];
  const f32x4 fz = {0.f, 0.f, 0.f, 0.f};
#pragma unroll
  for (int m = 0; m < 4; ++m)
#pragma unroll
    for (int n = 0; n < 4; ++n) acc[m][n] = fz;

#define G8_STAGE_A(SL, T)                                                      \
  do {                                                                         \
    unsigned short* sa_ = &smem[SL][(w * 8) * 64];                             \
    const unsigned short* g_ = gA + (size_t)(T) * 64;                          \
    glds16(g_, sa_);                                                           \
    glds16(g_ + 64 * D_MODEL, sa_ + 64 * 64);                                  \
  } while (0)

#define G8_STAGE_B(SL, T)                                                      \
  do {                                                                         \
    unsigned short* sb_ = &smem[SL][(128 + w * 8) * 64];                       \
    const unsigned short* g_ = gB + (size_t)(T) * 64;                          \
    glds16(g_, sb_);                                                           \
    glds16(g_ + 64 * D_MODEL, sb_ + 64 * 64);                                  \
    glds16(g_ + 128 * D_MODEL, sb_ + 128 * 64);                                \
    glds16(g_ + 192 * D_MODEL, sb_ + 192 * 64);                                \
  } while (0)

#define G8_PHASE(SL, KC, STG)                                                  \
  do {                                                                         \
    const unsigned short* As_ = &smem[SL][0];                                  \
    const unsigned short* Bs_ = &smem[SL][128 * 64];                           \
    bf16x8 af_[4], bf_[4];                                                     \
    _Pragma("unroll") for (int mi = 0; mi < 4; ++mi)                           \
      af_[mi] = ld8(As_ + (wm * 64 + mi * 16 + l15) * 64 + (KC));              \
    _Pragma("unroll") for (int ni = 0; ni < 4; ++ni)                           \
      bf_[ni] = ld8(Bs_ + (wn * 64 + ni * 16 + l15) * 64 + (KC));              \
    STG;                                                                       \
    __builtin_amdgcn_s_barrier();                                              \
    __builtin_amdgcn_s_setprio(1);                                             \
    _Pragma("unroll") for (int mi = 0; mi < 4; ++mi)                           \
      _Pragma("unroll") for (int ni = 0; ni < 4; ++ni)                         \
        acc[mi][ni] = __builtin_amdgcn_mfma_f32_16x16x32_bf16(                 \
            af_[mi], bf_[ni], acc[mi][ni], 0, 0, 0);                           \
    __builtin_amdgcn_s_setprio(0);                                             \
    __builtin_amdgcn_s_barrier();                                              \
  } while (0)

  // Prologue: tiles 0,1 -> slots 0,1 (12 loads/thread in flight)
  G8_STAGE_A(0, 0); G8_STAGE_B(0, 0);
  G8_STAGE_A(1, 1); G8_STAGE_B(1, 1);

#pragma unroll
  for (int t = 0; t < 16; ++t) {
    const int sl = t % 3;
    const int sp = (t + 2) % 3;
    if (t < 15) {
      asm volatile("s_waitcnt vmcnt(6)" ::: "memory");  // tile t landed
    } else {
      asm volatile("s_waitcnt vmcnt(0)" ::: "memory");  // final drain
    }
    __builtin_amdgcn_s_barrier();
    if (t < 14) {
      G8_PHASE(sl, kc0, G8_STAGE_A(sp, (t + 2)));
      G8_PHASE(sl, kc1, G8_STAGE_B(sp, (t + 2)));
    } else {
      G8_PHASE(sl, kc0, ((void)0));
      G8_PHASE(sl, kc1, ((void)0));
    }
  }
#undef G8_STAGE_A
#undef G8_STAGE_B
#undef G8_PHASE

  // ---------------- epilogue: rope (Q/K) or transpose (V), one 64x64 per wave
  unsigned short(*T)[68] =
      (unsigned short(*)[68])(&smem[0][0] + w * 4352);  // 64x68 per wave
  const int gcb = col0 + wn * 64;  // 64-aligned -> one head per wave
  const bool isV = (gcb >= 2048);
  const int lr = lane >> 3;
  const int lc = lane & 7;

  if (!isV) {
#pragma unroll
    for (int mi = 0; mi < 4; ++mi)
#pragma unroll
      for (int n = 0; n < 4; ++n)
#pragma unroll
        for (int r = 0; r < 4; ++r)
          T[mi * 16 + l4 * 4 + r][n * 16 + l15] = f2bf(acc[mi][n][r]);
  } else {
#pragma unroll
    for (int mi = 0; mi < 4; ++mi)
#pragma unroll
      for (int n = 0; n < 4; ++n)
#pragma unroll
        for (int r = 0; r < 4; ++r)
          T[n * 16 + l15][mi * 16 + l4 * 4 + r] = f2bf(acc[mi][n][r]);
  }
  if (!isV) {
    const bool isQ = (gcb < 1024);
    unsigned short* O = isQ ? Qo : Ko;
    // fold softmax scale into Q: 1/sqrt(64) * log2(e)
    const float qs = isQ ? 0.18033688011112042f : 1.0f;
    const int cbase = gcb & 1023;
#pragma unroll
    for (int rg = 0; rg < 8; ++rg) {
      const int trow = rg * 8 + lr;
      const int grow = row0 + wm * 64 + trow;
      const int s = grow & (S_LEN - 1);
      const bf16x8 vv = ld8(&T[trow][lc * 8]);
      const float4 tA = *reinterpret_cast<const float4*>(&tab[s * 32 + lc * 4]);
      const float4 tB = *reinterpret_cast<const float4*>(&tab[s * 32 + lc * 4 + 2]);
      float x[8];
#pragma unroll
      for (int j = 0; j < 8; ++j) x[j] = bf2f((unsigned short)vv[j]);
      union { unsigned int u[4]; uint4 v; } o;
      o.u[0] = pkbf((x[0] * tA.x - x[1] * tA.y) * qs, (x[0] * tA.y + x[1] * tA.x) * qs);
      o.u[1] = pkbf((x[2] * tA.z - x[3] * tA.w) * qs, (x[2] * tA.w + x[3] * tA.z) * qs);
      o.u[2] = pkbf((x[4] * tB.x - x[5] * tB.y) * qs, (x[4] * tB.y + x[5] * tB.x) * qs);
      o.u[3] = pkbf((x[6] * tB.z - x[7] * tB.w) * qs, (x[6] * tB.w + x[7] * tB.z) * qs);
      *reinterpret_cast<uint4*>(O + (size_t)grow * D_MODEL + cbase + lc * 8) = o.v;
    }
  } else {
    const int vc0 = gcb - 2048;
    const int h = vc0 >> 6;
    const int bb = row0 >> 11;
    const int s0 = (row0 & (S_LEN - 1)) + wm * 64;
#pragma unroll
    for (int rg = 0; rg < 8; ++rg) {
      const int dk = rg * 8 + lr;
      const bf16x8 vv = ld8(&T[dk][lc * 8]);
      *reinterpret_cast<bf16x8*>(
          VTo + ((size_t)((bb << 4) + h) * 64 + dk) * S_LEN + s0 + lc * 8) = vv;
    }
  }
}

// ---------------------------------------------------------------- attention
// attn6 (best measured, 84.4us): flash, causal, no running max (Q pre-scaled
// by 0.125*log2e).  8 waves x 16 q = 128 q/block, 512 blocks = 2 blocks/CU.
// S^T (A=K, B=Q): lane holds q=l15, key=l4*4+r -> P feeds PV in-register.
__global__ __launch_bounds__(512) void attn6_k(
    const unsigned short* __restrict__ Q, const unsigned short* __restrict__ K,
    const unsigned short* __restrict__ VT, unsigned short* __restrict__ O) {
  const int pair = blockIdx.x;  // 0..7
  const int h = blockIdx.y;
  const int b = blockIdx.z;
  const int tid = threadIdx.x;
  const int w = tid >> 6;       // 0..7
  const int lane = tid & 63;
  const int l15 = lane & 15;
  const int l4 = lane >> 4;

  __shared__ __align__(16) unsigned short Ks[64][72];
  __shared__ __align__(16) unsigned short Vs[64][72];  // Vs[dk][key]
#if !HAVE_MFMA16
  __shared__ __align__(16) unsigned short Ps[8][16][72];
#endif

  const f32x4 fz = {0.f, 0.f, 0.f, 0.f};
  const unsigned short* kbase = K + (size_t)b * S_LEN * D_MODEL + h * D_HEAD;
  const unsigned short* vbase = VT + (size_t)((b << 4) + h) * 64 * S_LEN;

  const int rr = tid >> 3;        // staging row 0..63 (512 thr cover 64x64)
  const int c8 = (tid & 7) * 8;   // staging 8-short chunk

  for (int half = 0; half < 2; ++half) {
    const int qt = half ? (15 - pair) : pair;
    const int qb = qt * 128;
    const int qw0 = qb + w * 16;

    bf16x8 qf[2];
#pragma unroll
    for (int kc = 0; kc < 2; ++kc)
      qf[kc] = ld8(Q + (size_t)(b * S_LEN + qw0 + l15) * D_MODEL +
                   h * D_HEAD + kc * 32 + l4 * 8);

    f32x4 o[4];
#pragma unroll
    for (int d = 0; d < 4; ++d) o[d] = fz;
    float lsum = 0.f;

    const int nkt = qb / 64 + 2;
    // prefetch tile 0
    uint4 kreg = *reinterpret_cast<const uint4*>(kbase + (size_t)rr * D_MODEL + c8);
    uint4 vreg = *reinterpret_cast<const uint4*>(vbase + (size_t)rr * S_LEN + c8);

    for (int kt = 0; kt < nkt; ++kt) {
      const int kb0 = kt * 64;
      *reinterpret_cast<uint4*>(&Ks[rr][c8]) = kreg;
      *reinterpret_cast<uint4*>(&Vs[rr][c8]) = vreg;
      if (kt + 1 < nkt) {  // prefetch next tile; hides behind this tile's math
        const int nb0 = kb0 + 64;
        kreg = *reinterpret_cast<const uint4*>(kbase + (size_t)(nb0 + rr) * D_MODEL + c8);
        vreg = *reinterpret_cast<const uint4*>(vbase + (size_t)rr * S_LEN + nb0 + c8);
      }
      __syncthreads();

      if (kb0 <= qw0 + 15) {
        // ---- S^T = K Q^T : lane holds q=l15, key=kb0+n*16+l4*4+r
        f32x4 s[4];
#pragma unroll
        for (int n = 0; n < 4; ++n) {
          const bf16x8 kf0 = ld8(&Ks[n * 16 + l15][l4 * 8]);
          const bf16x8 kf1 = ld8(&Ks[n * 16 + l15][32 + l4 * 8]);
          f32x4 a0 = __builtin_amdgcn_mfma_f32_16x16x32_bf16(kf0, qf[0], fz, 0, 0, 0);
          s[n] = __builtin_amdgcn_mfma_f32_16x16x32_bf16(kf1, qf[1], a0, 0, 0, 0);
        }
        // ---- exp2 + causal mask + per-lane row-sum + pack to bf16
        bf16x4 pf[4];
        const bool full = (kb0 + 63 <= qw0);
        const int q = qw0 + l15;
        float su = lsum;
#pragma unroll
        for (int n = 0; n < 4; ++n) {
          float e[4];
          if (full) {
#pragma unroll
            for (int r = 0; r < 4; ++r) e[r] = exp2f(s[n][r]);
          } else {
#pragma unroll
            for (int r = 0; r < 4; ++r) {
              const int key = kb0 + n * 16 + l4 * 4 + r;
              const float v = exp2f(s[n][r]);
              e[r] = (key <= q) ? v : 0.f;
            }
          }
          su += (e[0] + e[1]) + (e[2] + e[3]);
          union { unsigned int u[2]; bf16x4 v; } pk;
          pk.u[0] = pkbf(e[0], e[1]);
          pk.u[1] = pkbf(e[2], e[3]);
          pf[n] = pk.v;
        }
        lsum = su;

        // ---- O^T += V^T P^T (P in-register as B-operand)
#if HAVE_MFMA16
#pragma unroll
        for (int d = 0; d < 4; ++d) {
          bf16x4 vfc[4];
#pragma unroll
          for (int c = 0; c < 4; ++c) vfc[c] = ld4(&Vs[d * 16 + l15][c * 16 + l4 * 4]);
#pragma unroll
          for (int c = 0; c < 4; ++c)
            o[d] = __builtin_amdgcn_mfma_f32_16x16x16bf16_1k(vfc[c], pf[c], o[d], 0, 0, 0);
        }
#else
#pragma unroll
        for (int n = 0; n < 4; ++n)
          *reinterpret_cast<bf16x4*>(&Ps[w][l15][n * 16 + l4 * 4]) = pf[n];
        bf16x8 pfr[2];
#pragma unroll
        for (int kc = 0; kc < 2; ++kc)
          pfr[kc] = ld8(&Ps[w][l15][kc * 32 + l4 * 8]);
#pragma unroll
        for (int d = 0; d < 4; ++d) {
          const bf16x8 vf0 = ld8(&Vs[d * 16 + l15][l4 * 8]);
          const bf16x8 vf1 = ld8(&Vs[d * 16 + l15][32 + l4 * 8]);
          o[d] = __builtin_amdgcn_mfma_f32_16x16x32_bf16(vf0, pfr[0], o[d], 0, 0, 0);
          o[d] = __builtin_amdgcn_mfma_f32_16x16x32_bf16(vf1, pfr[1], o[d], 0, 0, 0);
        }
#endif
      }
      __syncthreads();
    }

    // lsum lives per-lane at q=l15; reduce across quads (lane bits 4,5)
    float s = lsum;
    s += __shfl_xor(s, 16);
    s += __shfl_xor(s, 32);
    const float li = 1.0f / s;
    unsigned short* op = O + (size_t)(b * S_LEN + qw0 + l15) * D_MODEL +
                         h * D_HEAD + l4 * 4;
#pragma unroll
    for (int d = 0; d < 4; ++d) {
      union { unsigned int u[2]; uint2 v; } ov;
      ov.u[0] = pkbf(o[d][0] * li, o[d][1] * li);
      ov.u[1] = pkbf(o[d][2] * li, o[d][3] * li);
      *reinterpret_cast<uint2*>(op + d * 16) = ov.v;
    }
  }
}

// ---------------------------------------------------------------- launch
extern "C" void kernel_launch(void* const* d_in, const int* in_sizes, int n_in,
                              void* d_out, int out_size, void* d_ws, size_t ws_size,
                              hipStream_t stream) {
  const float* x  = (const float*)d_in[0];
  const float* Wq = (const float*)d_in[1];
  const float* Wk = (const float*)d_in[2];
  const float* Wv = (const float*)d_in[3];
  const float* Wo = (const float*)d_in[4];
  const int* pos  = (const int*)d_in[5];
  float* out = (float*)d_out;

  char* ws = (char*)d_ws;
  const size_t big = (size_t)M_ROWS * D_MODEL * 2;  // 16 MiB
  const size_t wsz = (size_t)D_MODEL * D_MODEL * 2; // 2 MiB
  unsigned short* xb  = (unsigned short*)(ws + 0 * big);
  unsigned short* Qb  = (unsigned short*)(ws + 1 * big);  // attn out aliases Qb
  unsigned short* Kb  = (unsigned short*)(ws + 2 * big);
  unsigned short* VT  = (unsigned short*)(ws + 3 * big);
  unsigned short* Wqkvt = (unsigned short*)(ws + 4 * big);
  unsigned short* Wot   = (unsigned short*)(ws + 4 * big + 3 * wsz);
  float2* tab = (float2*)d_out;  // free scratch until final projection

  rope_tab_k<<<dim3(S_LEN * 32 / 256), 256, 0, stream>>>(pos, tab);
  cast_k<<<dim3(M_ROWS * D_MODEL / 2048), 256, 0, stream>>>(x, xb);
  wtrans_k<<<dim3(16, 16, 4), 256, 0, stream>>>(
      Wq, Wk, Wv, Wo, Wqkvt, Wqkvt + (size_t)D_MODEL * D_MODEL,
      Wqkvt + 2 * (size_t)D_MODEL * D_MODEL, Wot);
  gemm8_k<<<dim3(M_ROWS / 128, 3 * D_MODEL / 256), 512, 0, stream>>>(
      xb, Wqkvt, Qb, Kb, VT, tab);
  attn6_k<<<dim3(8, N_HEAD, B_N), 512, 0, stream>>>(Qb, Kb, VT, Qb);
  gemm2_k<<<dim3(M_ROWS / 128, D_MODEL / 128), 256, 0, stream>>>(Qb, Wot, out);
}

// Round 10
// 254.182 us; speedup vs baseline: 1.7939x; 1.0409x over previous
//
#include <hip/hip_runtime.h>
#include <hip/hip_bf16.h>

#define B_N 4
#define S_LEN 2048
#define D_MODEL 1024
#define N_HEAD 16
#define D_HEAD 64
#define M_ROWS (B_N * S_LEN) /* 8192 */

typedef short bf16x8 __attribute__((ext_vector_type(8)));
typedef short bf16x4 __attribute__((ext_vector_type(4)));
typedef float f32x4 __attribute__((ext_vector_type(4)));

#if __has_builtin(__builtin_amdgcn_mfma_f32_16x16x16bf16_1k)
#define HAVE_MFMA16 1
#else
#define HAVE_MFMA16 0
#endif

__device__ __forceinline__ unsigned short f2bf(float f) {
  union { float f; unsigned int u; } v; v.f = f;
  unsigned int r = v.u + 0x7FFFu + ((v.u >> 16) & 1u);
  return (unsigned short)(r >> 16);
}
__device__ __forceinline__ float bf2f(unsigned short u) {
  union { unsigned int u; float f; } v; v.u = ((unsigned int)u) << 16;
  return v.f;
}
// packed f32x2 -> bf16x2 (v_cvt_pk_bf16_f32, RNE)
__device__ __forceinline__ unsigned int pkbf(float a, float b) {
  union { __hip_bfloat162 h; unsigned int u; } cv;
  cv.h = __float22bfloat162_rn(make_float2(a, b));
  return cv.u;
}
__device__ __forceinline__ bf16x8 ld8(const unsigned short* p) {
  return *reinterpret_cast<const bf16x8*>(p);
}
__device__ __forceinline__ bf16x4 ld4(const unsigned short* p) {
  return *reinterpret_cast<const bf16x4*>(p);
}
__device__ __forceinline__ void glds16(const unsigned short* g, unsigned short* l) {
  __builtin_amdgcn_global_load_lds(
      (const __attribute__((address_space(1))) unsigned int*)g,
      (__attribute__((address_space(3))) unsigned int*)l, 16, 0, 0);
}

// ---------------------------------------------------------------- rope table
__global__ __launch_bounds__(256) void rope_tab_k(const int* __restrict__ pos,
                                                  float2* __restrict__ tab) {
  const int idx = blockIdx.x * 256 + threadIdx.x;
  const int s = idx >> 5;
  const int i = idx & 31;
  const float inv = exp2f(-(float)i * 0.41524101186092029f);  // log2(1e4)/32
  const float ang = (float)pos[s] * inv;
  tab[idx] = make_float2(cosf(ang), sinf(ang));
}

// ---------------------------------------------------------------- cast x
__global__ __launch_bounds__(256) void cast_k(const float* __restrict__ X,
                                              unsigned short* __restrict__ Y) {
  const size_t i = ((size_t)blockIdx.x * 256 + threadIdx.x) * 8;
  const float4 a = *reinterpret_cast<const float4*>(X + i);
  const float4 b = *reinterpret_cast<const float4*>(X + i + 4);
  union { unsigned int u[4]; uint4 v; } o;
  o.u[0] = pkbf(a.x, a.y); o.u[1] = pkbf(a.z, a.w);
  o.u[2] = pkbf(b.x, b.y); o.u[3] = pkbf(b.z, b.w);
  *reinterpret_cast<uint4*>(Y + i) = o.v;
}

// ---------------------------------------------------------------- transpose
__global__ __launch_bounds__(256) void wtrans_k(
    const float* __restrict__ W0, const float* __restrict__ W1,
    const float* __restrict__ W2, const float* __restrict__ W3,
    unsigned short* __restrict__ T0, unsigned short* __restrict__ T1,
    unsigned short* __restrict__ T2, unsigned short* __restrict__ T3) {
  const int z = blockIdx.z;
  const float* __restrict__ W = (z == 0) ? W0 : (z == 1) ? W1 : (z == 2) ? W2 : W3;
  unsigned short* __restrict__ T = (z == 0) ? T0 : (z == 1) ? T1 : (z == 2) ? T2 : T3;
  __shared__ __align__(16) unsigned short tile[64][72];
  const int kb = blockIdx.x * 64;
  const int nb = blockIdx.y * 64;
#pragma unroll
  for (int it = 0; it < 2; ++it) {
    const int chunk = it * 256 + threadIdx.x;
    const int r = chunk >> 3;
    const int c8 = (chunk & 7) * 8;
    const float* src = W + (size_t)(kb + r) * D_MODEL + nb + c8;
    const float4 a = *reinterpret_cast<const float4*>(src);
    const float4 b = *reinterpret_cast<const float4*>(src + 4);
    union { unsigned int u[4]; uint4 v; } o;
    o.u[0] = pkbf(a.x, a.y); o.u[1] = pkbf(a.z, a.w);
    o.u[2] = pkbf(b.x, b.y); o.u[3] = pkbf(b.z, b.w);
    *reinterpret_cast<uint4*>(&tile[r][c8]) = o.v;
  }
  __syncthreads();
#pragma unroll
  for (int it = 0; it < 2; ++it) {
    const int chunk = it * 256 + threadIdx.x;
    const int n = chunk >> 3;
    const int k8 = (chunk & 7) * 8;
    __align__(16) unsigned short vals[8];
#pragma unroll
    for (int j = 0; j < 8; ++j) vals[j] = tile[k8 + j][n];
    *reinterpret_cast<uint4*>(T + (size_t)(nb + n) * D_MODEL + kb + k8) =
        *reinterpret_cast<const uint4*>(vals);
  }
}

// ---------------------------------------------------------------- GEMM
// 128x256 tile, BK=64, 8 waves (2M x 4N).  Per K-tile: 2 phases (one per
// K-half), each {8x ds_read_b128 (swizzled) | stage burst | barrier |
// setprio(1) 16x MFMA setprio(0) | barrier} -- full-hold fragments, zero
// redundant LDS reads.  LDS: 3 slots; tile t reads slot t%3 while staging
// t+2 into (t+2)%3.  Counted vmcnt(6) per tile head; vmcnt(0) only at the
// final tile.  Bank swizzle: physical 16B chunk = logical ^ (row&7) on BOTH
// sides (stage source pre-swizzle + ds_read address).
// Two epilogues: OF==null -> QKV mode (rope Q/K, transpose V);
//                OF!=null -> fp32 out-projection write.
// (Round-4 verified schedule, ~83us @ grid 64x12.  Proj reuse: grid 64x4 =
// 256 blocks = exactly 1 round at 1 block/CU.)
__global__ __launch_bounds__(512, 1) void gemm8_k(
    const unsigned short* __restrict__ A, const unsigned short* __restrict__ W,
    unsigned short* __restrict__ Qo, unsigned short* __restrict__ Ko,
    unsigned short* __restrict__ VTo, float* __restrict__ OF,
    const float2* __restrict__ tab) {
  __shared__ __align__(16) unsigned short smem[3][384 * 64];  // 144 KiB

  const int tid = threadIdx.x;
  const int lane = tid & 63;
  const int w = tid >> 6;   // 0..7
  const int l15 = lane & 15;
  const int l4 = lane >> 4;
  const int wm = w >> 2;    // 0..1 : 64-row half
  const int wn = w & 3;     // 0..3 : 64-col quarter

  const int row0 = blockIdx.x * 128;
  const int col0 = blockIdx.y * 256;

  const int srow = lane >> 3;            // 0..7  == row&7 of the staged row
  const int schunk = (lane & 7) ^ srow;  // swizzled 16B chunk in the row
  const unsigned short* gA = A + (size_t)(row0 + w * 8 + srow) * D_MODEL + schunk * 8;
  const unsigned short* gB = W + (size_t)(col0 + w * 8 + srow) * D_MODEL + schunk * 8;

  const int swz = l15 & 7;
  const int kc0 = ((l4) ^ swz) * 8;
  const int kc1 = ((l4 + 4) ^ swz) * 8;

  f32x4 acc[4][4];
  const f32x4 fz = {0.f, 0.f, 0.f, 0.f};
#pragma unroll
  for (int m = 0; m < 4; ++m)
#pragma unroll
    for (int n = 0; n < 4; ++n) acc[m][n] = fz;

#define G8_STAGE_A(SL, T)                                                      \
  do {                                                                         \
    unsigned short* sa_ = &smem[SL][(w * 8) * 64];                             \
    const unsigned short* g_ = gA + (size_t)(T) * 64;                          \
    glds16(g_, sa_);                                                           \
    glds16(g_ + 64 * D_MODEL, sa_ + 64 * 64);                                  \
  } while (0)

#define G8_STAGE_B(SL, T)                                                      \
  do {                                                                         \
    unsigned short* sb_ = &smem[SL][(128 + w * 8) * 64];                       \
    const unsigned short* g_ = gB + (size_t)(T) * 64;                          \
    glds16(g_, sb_);                                                           \
    glds16(g_ + 64 * D_MODEL, sb_ + 64 * 64);                                  \
    glds16(g_ + 128 * D_MODEL, sb_ + 128 * 64);                                \
    glds16(g_ + 192 * D_MODEL, sb_ + 192 * 64);                                \
  } while (0)

#define G8_PHASE(SL, KC, STG)                                                  \
  do {                                                                         \
    const unsigned short* As_ = &smem[SL][0];                                  \
    const unsigned short* Bs_ = &smem[SL][128 * 64];                           \
    bf16x8 af_[4], bf_[4];                                                     \
    _Pragma("unroll") for (int mi = 0; mi < 4; ++mi)                           \
      af_[mi] = ld8(As_ + (wm * 64 + mi * 16 + l15) * 64 + (KC));              \
    _Pragma("unroll") for (int ni = 0; ni < 4; ++ni)                           \
      bf_[ni] = ld8(Bs_ + (wn * 64 + ni * 16 + l15) * 64 + (KC));              \
    STG;                                                                       \
    __builtin_amdgcn_s_barrier();                                              \
    __builtin_amdgcn_s_setprio(1);                                             \
    _Pragma("unroll") for (int mi = 0; mi < 4; ++mi)                           \
      _Pragma("unroll") for (int ni = 0; ni < 4; ++ni)                         \
        acc[mi][ni] = __builtin_amdgcn_mfma_f32_16x16x32_bf16(                 \
            af_[mi], bf_[ni], acc[mi][ni], 0, 0, 0);                           \
    __builtin_amdgcn_s_setprio(0);                                             \
    __builtin_amdgcn_s_barrier();                                              \
  } while (0)

  // Prologue: tiles 0,1 -> slots 0,1 (12 loads/thread in flight)
  G8_STAGE_A(0, 0); G8_STAGE_B(0, 0);
  G8_STAGE_A(1, 1); G8_STAGE_B(1, 1);

#pragma unroll
  for (int t = 0; t < 16; ++t) {
    const int sl = t % 3;
    const int sp = (t + 2) % 3;
    if (t < 15) {
      asm volatile("s_waitcnt vmcnt(6)" ::: "memory");  // tile t landed
    } else {
      asm volatile("s_waitcnt vmcnt(0)" ::: "memory");  // final drain
    }
    __builtin_amdgcn_s_barrier();
    if (t < 14) {
      G8_PHASE(sl, kc0, G8_STAGE_A(sp, (t + 2)));
      G8_PHASE(sl, kc1, G8_STAGE_B(sp, (t + 2)));
    } else {
      G8_PHASE(sl, kc0, ((void)0));
      G8_PHASE(sl, kc1, ((void)0));
    }
  }
#undef G8_STAGE_A
#undef G8_STAGE_B
#undef G8_PHASE

  // ---------------- epilogue A: out-projection, fp32 (same C-layout as QKV)
  if (OF) {
#pragma unroll
    for (int ni = 0; ni < 4; ++ni) {
      const int gcol = col0 + wn * 64 + ni * 16 + l15;
#pragma unroll
      for (int mi = 0; mi < 4; ++mi)
#pragma unroll
        for (int r = 0; r < 4; ++r)
          OF[(size_t)(row0 + wm * 64 + mi * 16 + l4 * 4 + r) * D_MODEL + gcol] =
              acc[mi][ni][r];
    }
    return;
  }

  // ---------------- epilogue B: rope (Q/K) or transpose (V), 64x64 per wave
  unsigned short(*T)[68] =
      (unsigned short(*)[68])(&smem[0][0] + w * 4352);  // 64x68 per wave
  const int gcb = col0 + wn * 64;  // 64-aligned -> one head per wave
  const bool isV = (gcb >= 2048);
  const int lr = lane >> 3;
  const int lc = lane & 7;

  if (!isV) {
#pragma unroll
    for (int mi = 0; mi < 4; ++mi)
#pragma unroll
      for (int n = 0; n < 4; ++n)
#pragma unroll
        for (int r = 0; r < 4; ++r)
          T[mi * 16 + l4 * 4 + r][n * 16 + l15] = f2bf(acc[mi][n][r]);
  } else {
#pragma unroll
    for (int mi = 0; mi < 4; ++mi)
#pragma unroll
      for (int n = 0; n < 4; ++n)
#pragma unroll
        for (int r = 0; r < 4; ++r)
          T[n * 16 + l15][mi * 16 + l4 * 4 + r] = f2bf(acc[mi][n][r]);
  }
  if (!isV) {
    const bool isQ = (gcb < 1024);
    unsigned short* O = isQ ? Qo : Ko;
    // fold softmax scale into Q: 1/sqrt(64) * log2(e)
    const float qs = isQ ? 0.18033688011112042f : 1.0f;
    const int cbase = gcb & 1023;
#pragma unroll
    for (int rg = 0; rg < 8; ++rg) {
      const int trow = rg * 8 + lr;
      const int grow = row0 + wm * 64 + trow;
      const int s = grow & (S_LEN - 1);
      const bf16x8 vv = ld8(&T[trow][lc * 8]);
      const float4 tA = *reinterpret_cast<const float4*>(&tab[s * 32 + lc * 4]);
      const float4 tB = *reinterpret_cast<const float4*>(&tab[s * 32 + lc * 4 + 2]);
      float x[8];
#pragma unroll
      for (int j = 0; j < 8; ++j) x[j] = bf2f((unsigned short)vv[j]);
      union { unsigned int u[4]; uint4 v; } o;
      o.u[0] = pkbf((x[0] * tA.x - x[1] * tA.y) * qs, (x[0] * tA.y + x[1] * tA.x) * qs);
      o.u[1] = pkbf((x[2] * tA.z - x[3] * tA.w) * qs, (x[2] * tA.w + x[3] * tA.z) * qs);
      o.u[2] = pkbf((x[4] * tB.x - x[5] * tB.y) * qs, (x[4] * tB.y + x[5] * tB.x) * qs);
      o.u[3] = pkbf((x[6] * tB.z - x[7] * tB.w) * qs, (x[6] * tB.w + x[7] * tB.z) * qs);
      *reinterpret_cast<uint4*>(O + (size_t)grow * D_MODEL + cbase + lc * 8) = o.v;
    }
  } else {
    const int vc0 = gcb - 2048;
    const int h = vc0 >> 6;
    const int bb = row0 >> 11;
    const int s0 = (row0 & (S_LEN - 1)) + wm * 64;
#pragma unroll
    for (int rg = 0; rg < 8; ++rg) {
      const int dk = rg * 8 + lr;
      const bf16x8 vv = ld8(&T[dk][lc * 8]);
      *reinterpret_cast<bf16x8*>(
          VTo + ((size_t)((bb << 4) + h) * 64 + dk) * S_LEN + s0 + lc * 8) = vv;
    }
  }
}

// ---------------------------------------------------------------- attention
// attn6 (best measured, 83.7us): flash, causal, no running max (Q pre-scaled
// by 0.125*log2e).  8 waves x 16 q = 128 q/block, 512 blocks = 2 blocks/CU.
// S^T (A=K, B=Q): lane holds q=l15, key=l4*4+r -> P feeds PV in-register.
__global__ __launch_bounds__(512) void attn6_k(
    const unsigned short* __restrict__ Q, const unsigned short* __restrict__ K,
    const unsigned short* __restrict__ VT, unsigned short* __restrict__ O) {
  const int pair = blockIdx.x;  // 0..7
  const int h = blockIdx.y;
  const int b = blockIdx.z;
  const int tid = threadIdx.x;
  const int w = tid >> 6;       // 0..7
  const int lane = tid & 63;
  const int l15 = lane & 15;
  const int l4 = lane >> 4;

  __shared__ __align__(16) unsigned short Ks[64][72];
  __shared__ __align__(16) unsigned short Vs[64][72];  // Vs[dk][key]
#if !HAVE_MFMA16
  __shared__ __align__(16) unsigned short Ps[8][16][72];
#endif

  const f32x4 fz = {0.f, 0.f, 0.f, 0.f};
  const unsigned short* kbase = K + (size_t)b * S_LEN * D_MODEL + h * D_HEAD;
  const unsigned short* vbase = VT + (size_t)((b << 4) + h) * 64 * S_LEN;

  const int rr = tid >> 3;        // staging row 0..63 (512 thr cover 64x64)
  const int c8 = (tid & 7) * 8;   // staging 8-short chunk

  for (int half = 0; half < 2; ++half) {
    const int qt = half ? (15 - pair) : pair;
    const int qb = qt * 128;
    const int qw0 = qb + w * 16;

    bf16x8 qf[2];
#pragma unroll
    for (int kc = 0; kc < 2; ++kc)
      qf[kc] = ld8(Q + (size_t)(b * S_LEN + qw0 + l15) * D_MODEL +
                   h * D_HEAD + kc * 32 + l4 * 8);

    f32x4 o[4];
#pragma unroll
    for (int d = 0; d < 4; ++d) o[d] = fz;
    float lsum = 0.f;

    const int nkt = qb / 64 + 2;
    // prefetch tile 0
    uint4 kreg = *reinterpret_cast<const uint4*>(kbase + (size_t)rr * D_MODEL + c8);
    uint4 vreg = *reinterpret_cast<const uint4*>(vbase + (size_t)rr * S_LEN + c8);

    for (int kt = 0; kt < nkt; ++kt) {
      const int kb0 = kt * 64;
      *reinterpret_cast<uint4*>(&Ks[rr][c8]) = kreg;
      *reinterpret_cast<uint4*>(&Vs[rr][c8]) = vreg;
      if (kt + 1 < nkt) {  // prefetch next tile; hides behind this tile's math
        const int nb0 = kb0 + 64;
        kreg = *reinterpret_cast<const uint4*>(kbase + (size_t)(nb0 + rr) * D_MODEL + c8);
        vreg = *reinterpret_cast<const uint4*>(vbase + (size_t)rr * S_LEN + nb0 + c8);
      }
      __syncthreads();

      if (kb0 <= qw0 + 15) {
        // ---- S^T = K Q^T : lane holds q=l15, key=kb0+n*16+l4*4+r
        f32x4 s[4];
#pragma unroll
        for (int n = 0; n < 4; ++n) {
          const bf16x8 kf0 = ld8(&Ks[n * 16 + l15][l4 * 8]);
          const bf16x8 kf1 = ld8(&Ks[n * 16 + l15][32 + l4 * 8]);
          f32x4 a0 = __builtin_amdgcn_mfma_f32_16x16x32_bf16(kf0, qf[0], fz, 0, 0, 0);
          s[n] = __builtin_amdgcn_mfma_f32_16x16x32_bf16(kf1, qf[1], a0, 0, 0, 0);
        }
        // ---- exp2 + causal mask + per-lane row-sum + pack to bf16
        bf16x4 pf[4];
        const bool full = (kb0 + 63 <= qw0);
        const int q = qw0 + l15;
        float su = lsum;
#pragma unroll
        for (int n = 0; n < 4; ++n) {
          float e[4];
          if (full) {
#pragma unroll
            for (int r = 0; r < 4; ++r) e[r] = exp2f(s[n][r]);
          } else {
#pragma unroll
            for (int r = 0; r < 4; ++r) {
              const int key = kb0 + n * 16 + l4 * 4 + r;
              const float v = exp2f(s[n][r]);
              e[r] = (key <= q) ? v : 0.f;
            }
          }
          su += (e[0] + e[1]) + (e[2] + e[3]);
          union { unsigned int u[2]; bf16x4 v; } pk;
          pk.u[0] = pkbf(e[0], e[1]);
          pk.u[1] = pkbf(e[2], e[3]);
          pf[n] = pk.v;
        }
        lsum = su;

        // ---- O^T += V^T P^T (P in-register as B-operand)
#if HAVE_MFMA16
#pragma unroll
        for (int d = 0; d < 4; ++d) {
          bf16x4 vfc[4];
#pragma unroll
          for (int c = 0; c < 4; ++c) vfc[c] = ld4(&Vs[d * 16 + l15][c * 16 + l4 * 4]);
#pragma unroll
          for (int c = 0; c < 4; ++c)
            o[d] = __builtin_amdgcn_mfma_f32_16x16x16bf16_1k(vfc[c], pf[c], o[d], 0, 0, 0);
        }
#else
#pragma unroll
        for (int n = 0; n < 4; ++n)
          *reinterpret_cast<bf16x4*>(&Ps[w][l15][n * 16 + l4 * 4]) = pf[n];
        bf16x8 pfr[2];
#pragma unroll
        for (int kc = 0; kc < 2; ++kc)
          pfr[kc] = ld8(&Ps[w][l15][kc * 32 + l4 * 8]);
#pragma unroll
        for (int d = 0; d < 4; ++d) {
          const bf16x8 vf0 = ld8(&Vs[d * 16 + l15][l4 * 8]);
          const bf16x8 vf1 = ld8(&Vs[d * 16 + l15][32 + l4 * 8]);
          o[d] = __builtin_amdgcn_mfma_f32_16x16x32_bf16(vf0, pfr[0], o[d], 0, 0, 0);
          o[d] = __builtin_amdgcn_mfma_f32_16x16x32_bf16(vf1, pfr[1], o[d], 0, 0, 0);
        }
#endif
      }
      __syncthreads();
    }

    // lsum lives per-lane at q=l15; reduce across quads (lane bits 4,5)
    float s = lsum;
    s += __shfl_xor(s, 16);
    s += __shfl_xor(s, 32);
    const float li = 1.0f / s;
    unsigned short* op = O + (size_t)(b * S_LEN + qw0 + l15) * D_MODEL +
                         h * D_HEAD + l4 * 4;
#pragma unroll
    for (int d = 0; d < 4; ++d) {
      union { unsigned int u[2]; uint2 v; } ov;
      ov.u[0] = pkbf(o[d][0] * li, o[d][1] * li);
      ov.u[1] = pkbf(o[d][2] * li, o[d][3] * li);
      *reinterpret_cast<uint2*>(op + d * 16) = ov.v;
    }
  }
}

// ---------------------------------------------------------------- launch
extern "C" void kernel_launch(void* const* d_in, const int* in_sizes, int n_in,
                              void* d_out, int out_size, void* d_ws, size_t ws_size,
                              hipStream_t stream) {
  const float* x  = (const float*)d_in[0];
  const float* Wq = (const float*)d_in[1];
  const float* Wk = (const float*)d_in[2];
  const float* Wv = (const float*)d_in[3];
  const float* Wo = (const float*)d_in[4];
  const int* pos  = (const int*)d_in[5];
  float* out = (float*)d_out;

  char* ws = (char*)d_ws;
  const size_t big = (size_t)M_ROWS * D_MODEL * 2;  // 16 MiB
  const size_t wsz = (size_t)D_MODEL * D_MODEL * 2; // 2 MiB
  unsigned short* xb  = (unsigned short*)(ws + 0 * big);
  unsigned short* Qb  = (unsigned short*)(ws + 1 * big);  // attn out aliases Qb
  unsigned short* Kb  = (unsigned short*)(ws + 2 * big);
  unsigned short* VT  = (unsigned short*)(ws + 3 * big);
  unsigned short* Wqkvt = (unsigned short*)(ws + 4 * big);
  unsigned short* Wot   = (unsigned short*)(ws + 4 * big + 3 * wsz);
  float2* tab = (float2*)d_out;  // free scratch until final projection

  rope_tab_k<<<dim3(S_LEN * 32 / 256), 256, 0, stream>>>(pos, tab);
  cast_k<<<dim3(M_ROWS * D_MODEL / 2048), 256, 0, stream>>>(x, xb);
  wtrans_k<<<dim3(16, 16, 4), 256, 0, stream>>>(
      Wq, Wk, Wv, Wo, Wqkvt, Wqkvt + (size_t)D_MODEL * D_MODEL,
      Wqkvt + 2 * (size_t)D_MODEL * D_MODEL, Wot);
  gemm8_k<<<dim3(M_ROWS / 128, 3 * D_MODEL / 256), 512, 0, stream>>>(
      xb, Wqkvt, Qb, Kb, VT, nullptr, tab);
  attn6_k<<<dim3(8, N_HEAD, B_N), 512, 0, stream>>>(Qb, Kb, VT, Qb);
  gemm8_k<<<dim3(M_ROWS / 128, D_MODEL / 256), 512, 0, stream>>>(
      Qb, Wot, nullptr, nullptr, nullptr, out, nullptr);
}